// Round 7
// baseline (176.780 us; speedup 1.0000x reference)
//
#include <hip/hip_runtime.h>
#include <hip/hip_bf16.h>

// ---------------------------------------------------------------------------
// Problem constants.  Inputs f32, output f32 (proven R4).
// ---------------------------------------------------------------------------
#define BATCH 2
#define CCH   512
#define NSEQ  2048
#define HEADS 16
#define DHEAD 64
#define HDIM  1024
#define ODIM  3072
// 8 * log2(e): folded into q-hat at the GEMM epilogue; k_prep folds it into M2.
#define QK_PRESCALE 11.541560327111707f

typedef short short4v __attribute__((ext_vector_type(4)));
typedef short short8 __attribute__((ext_vector_type(8)));
typedef float float4v __attribute__((ext_vector_type(4)));

__device__ __forceinline__ unsigned short f2bf(float f) {          // RNE
    unsigned int u = __float_as_uint(f);
    return (unsigned short)((u + 0x7FFFu + ((u >> 16) & 1u)) >> 16);
}
__device__ __forceinline__ unsigned short f2bf_fast(float f) {     // round-half-up
    return (unsigned short)((__float_as_uint(f) + 0x8000u) >> 16);
}
__device__ __forceinline__ float fexp2(float x) {
#if __has_builtin(__builtin_amdgcn_exp2f)
    return __builtin_amdgcn_exp2f(x);
#else
    return exp2f(x);
#endif
}

typedef __attribute__((address_space(1))) const void* as1_cvp;
typedef __attribute__((address_space(3))) void* as3_vp;
__device__ __forceinline__ void cp16(const void* g, void* l) {
    __builtin_amdgcn_global_load_lds((as1_cvp)g, (as3_vp)l, 16, 0, 0);
}
// LDS XOR swizzle (R5, verified: SQ_LDS_BANK_CONFLICT -> 0): slot (row,chunk)
// holds global (row, chunk ^ (row&7)); staging lane fetches global chunk
// (tid&7)^((tid>>3)&7).

// ---------------------------------------------------------------------------
// k_convert_w: f32 -> bf16 for Wqkv then Wout; block 0 also computes
// M2 = QK_PRESCALE * max_d |qs_d*ks_d| (exact softmax bound, Cauchy-Schwarz).
// ---------------------------------------------------------------------------
__global__ __launch_bounds__(256) void k_convert_w(
    const float* __restrict__ Wqkv, const float* __restrict__ Wout,
    const float* __restrict__ qs, const float* __restrict__ ks,
    unsigned short* __restrict__ Wqkvb, unsigned short* __restrict__ Woutb,
    float* __restrict__ M) {
    if (blockIdx.x == 0 && threadIdx.x < 64) {
        int lane = threadIdx.x;
        float p = fabsf(qs[lane] * ks[lane]);
#pragma unroll
        for (int off = 1; off < 64; off <<= 1) p = fmaxf(p, __shfl_xor(p, off));
        if (lane == 0) *M = QK_PRESCALE * p;
    }
    int i4 = (blockIdx.x * 256 + threadIdx.x) * 4;
    const float* src; unsigned short* dst; int idx;
    if (i4 < ODIM * CCH) { src = Wqkv; dst = Wqkvb; idx = i4; }
    else { src = Wout; dst = Woutb; idx = i4 - ODIM * CCH; }
    float4 v = *(const float4*)(src + idx);
    ushort4 o;
    o.x = f2bf(v.x); o.y = f2bf(v.y); o.z = f2bf(v.z); o.w = f2bf(v.w);
    *(ushort4*)(dst + idx) = o;
}

// ---------------------------------------------------------------------------
// k_transpose_x: x [b][c][n] f32 -> xt [b][n][c] bf16
// ---------------------------------------------------------------------------
__global__ __launch_bounds__(256) void k_transpose_x(
    const float* __restrict__ x, unsigned short* __restrict__ xt) {
    __shared__ unsigned short t[64][65];
    const int b = blockIdx.z, c0 = blockIdx.y * 64, n0 = blockIdx.x * 64;
    const int tr = threadIdx.x >> 6, tc = threadIdx.x & 63;
    const float* xs = x + (size_t)b * CCH * NSEQ;
    unsigned short* xd = xt + (size_t)b * NSEQ * CCH;
#pragma unroll
    for (int r = 0; r < 16; ++r) {
        int c = r * 4 + tr;
        t[c][tc] = f2bf(xs[(size_t)(c0 + c) * NSEQ + n0 + tc]);
    }
    __syncthreads();
#pragma unroll
    for (int r = 0; r < 16; ++r) {
        int n = r * 4 + tr;
        xd[(size_t)(n0 + n) * CCH + c0 + tc] = t[tc][n];
    }
}

// ---------------------------------------------------------------------------
// k_gemm_qkv: fused QKV GEMM + l2-norm/scale + head repack.
// Epilogue uses per-wave LDS transpose (intra-wave only -> no barrier,
// swizzled chunks) so all global stores are full 128B rows.
//   q (part0): qh[bh][n][d] bf16, pre-scaled by QK_PRESCALE
//   k (part1): kh[bh][n][d] bf16
//   v (part2): vb[bh][d][n] bf16
// ---------------------------------------------------------------------------
__global__ __launch_bounds__(256) void k_gemm_qkv(
    const unsigned short* __restrict__ W, const unsigned short* __restrict__ xt,
    const float* __restrict__ qs, const float* __restrict__ ks,
    unsigned short* __restrict__ qh, unsigned short* __restrict__ kh,
    unsigned short* __restrict__ vb) {
    constexpr int K = CCH, N = NSEQ;
    __shared__ __align__(16) short smem[2 * 128 * 64];
    short* lsA = smem;
    short* lsB = smem + 128 * 64;
    const int tid = threadIdx.x, wave = tid >> 6, lane = tid & 63;
    const int l15 = lane & 15, quad = lane >> 4;
    const int n0 = blockIdx.x * 128, m0 = blockIdx.y * 128, z = blockIdx.z;
    const short* Ab = (const short*)W + (size_t)m0 * K;
    const short* Bb = (const short*)xt + ((size_t)z * N + n0) * K;
    const int wm = wave >> 1, wn = wave & 1;
    const int cswz = (((tid & 7) ^ ((tid >> 3) & 7))) * 8;
    const int sw7 = (l15 & 7);

    float4v acc[4][4];
#pragma unroll
    for (int i = 0; i < 4; ++i)
#pragma unroll
        for (int j = 0; j < 4; ++j) acc[i][j] = (float4v){0.f, 0.f, 0.f, 0.f};

    for (int k0 = 0; k0 < K; k0 += 64) {
#pragma unroll
        for (int it = 0; it < 4; ++it) {
            int row = it * 32 + (tid >> 3);
            cp16(Ab + (size_t)row * K + k0 + cswz, &lsA[it * 2048 + wave * 512]);
            cp16(Bb + (size_t)row * K + k0 + cswz, &lsB[it * 2048 + wave * 512]);
        }
        __syncthreads();
        short8 af[4][2], bfr[4][2];
#pragma unroll
        for (int t = 0; t < 4; ++t)
#pragma unroll
            for (int kk = 0; kk < 2; ++kk) {
                af[t][kk]  = *(const short8*)&lsA[(wm * 64 + t * 16 + l15) * 64 + ((kk * 4 + quad) ^ sw7) * 8];
                bfr[t][kk] = *(const short8*)&lsB[(wn * 64 + t * 16 + l15) * 64 + ((kk * 4 + quad) ^ sw7) * 8];
            }
#pragma unroll
        for (int mt = 0; mt < 4; ++mt)
#pragma unroll
            for (int nt = 0; nt < 4; ++nt) {
                acc[mt][nt] = __builtin_amdgcn_mfma_f32_16x16x32_bf16(af[mt][0], bfr[nt][0], acc[mt][nt], 0, 0, 0);
                acc[mt][nt] = __builtin_amdgcn_mfma_f32_16x16x32_bf16(af[mt][1], bfr[nt][1], acc[mt][nt], 0, 0, 0);
            }
        __syncthreads();
    }

    // ---- fused epilogue (per-wave 8KB LDS scratch; intra-wave, no barrier) --
    const int co   = (m0 + wm * 64) >> 6;   // chunk 0..47
    const int part = co >> 4;               // 0=q, 1=k, 2=v
    const int h    = co & 15;
    const int bh   = z * HEADS + h;
    short* myT = smem + wave * 4096;

    if (part < 2) {
        float inv[4];
#pragma unroll
        for (int nt = 0; nt < 4; ++nt) {
            float ss = 0.f;
#pragma unroll
            for (int mt = 0; mt < 4; ++mt)
#pragma unroll
                for (int r = 0; r < 4; ++r) ss += acc[mt][nt][r] * acc[mt][nt][r];
            ss += __shfl_xor(ss, 16);
            ss += __shfl_xor(ss, 32);
            inv[nt] = 1.0f / fmaxf(sqrtf(ss), 1e-12f);
        }
        const float* sc = part ? ks : qs;
        const float csc = part ? 1.0f : QK_PRESCALE;
#pragma unroll
        for (int mt = 0; mt < 4; ++mt) {
            const int db = mt * 16 + quad * 4;
            float4 s4 = *(const float4*)(sc + db);
            s4.x *= csc; s4.y *= csc; s4.z *= csc; s4.w *= csc;
#pragma unroll
            for (int nt = 0; nt < 4; ++nt) {
                int nl = nt * 16 + l15;
                short4v o;
                o.x = (short)f2bf(acc[mt][nt][0] * inv[nt] * s4.x);
                o.y = (short)f2bf(acc[mt][nt][1] * inv[nt] * s4.y);
                o.z = (short)f2bf(acc[mt][nt][2] * inv[nt] * s4.z);
                o.w = (short)f2bf(acc[mt][nt][3] * inv[nt] * s4.w);
                *(short4v*)&myT[nl * 64 + (((db >> 3) ^ (nl & 7)) << 3) + (db & 7)] = o;
            }
        }
        unsigned short* dst = (part ? kh : qh) + (size_t)bh * NSEQ * DHEAD
                              + (size_t)(n0 + wn * 64) * DHEAD;
#pragma unroll
        for (int pass = 0; pass < 8; ++pass) {
            int nl = pass * 8 + (lane >> 3), c = lane & 7;
            short8 vv = *(const short8*)&myT[nl * 64 + ((c ^ (nl & 7)) << 3)];
            *(short8*)&dst[(size_t)nl * DHEAD + c * 8] = vv;
        }
    } else {
#pragma unroll
        for (int mt = 0; mt < 4; ++mt)
#pragma unroll
            for (int nt = 0; nt < 4; ++nt) {
                int nl = nt * 16 + l15;
                int swc = nl >> 3, swo = nl & 7;
#pragma unroll
                for (int r = 0; r < 4; ++r) {
                    int d = mt * 16 + quad * 4 + r;
                    myT[d * 64 + ((swc ^ (d & 7)) << 3) + swo] = (short)f2bf(acc[mt][nt][r]);
                }
            }
        unsigned short* dst = vb + (size_t)bh * DHEAD * NSEQ + n0 + wn * 64;
#pragma unroll
        for (int pass = 0; pass < 8; ++pass) {
            int d = pass * 8 + (lane >> 3), c = lane & 7;
            short8 vv = *(const short8*)&myT[d * 64 + ((c ^ (d & 7)) << 3)];
            *(short8*)&dst[(size_t)d * NSEQ + c * 8] = vv;
        }
    }
}

// ---------------------------------------------------------------------------
// k_attn: fixed-M flash attention, j-split 2, swizzled LDS, XCD-local grid.
// q pre-scaled by 8*log2e and MFMA C-init = -M2  =>  p = exp2(s), 1 op.
// ---------------------------------------------------------------------------
__global__ __launch_bounds__(256, 4) void k_attn(
    const unsigned short* __restrict__ qh, const unsigned short* __restrict__ kh,
    const unsigned short* __restrict__ vb,
    float* __restrict__ opart, float* __restrict__ lpart,
    const float* __restrict__ Mptr) {
    __shared__ __align__(16) short Kt[64 * 64];
    __shared__ __align__(16) short Vt[64 * 64];
    __shared__ __align__(16) short Pt[128 * 64];
    const int tid = threadIdx.x, wave = tid >> 6, lane = tid & 63;
    const int l15 = lane & 15, quad = lane >> 4, q8 = quad * 8;
    const int flat = blockIdx.x;
    const int xcd = flat & 7, idx = flat >> 3;
    const int g = (xcd << 3) | (idx >> 4);
    const int i0 = (idx & 15) * 128;
    const int bh = g & 31, z = g >> 5;
    const float Ms = *Mptr;
    const float4v mInit = (float4v){-Ms, -Ms, -Ms, -Ms};
    const int cswz = (((tid & 7) ^ ((tid >> 3) & 7))) * 8;
    const int sw7 = (l15 & 7);

    short8 qf[2][2];
    const short* qb = (const short*)qh + ((size_t)bh * NSEQ + i0 + wave * 32) * DHEAD;
#pragma unroll
    for (int mt = 0; mt < 2; ++mt)
#pragma unroll
        for (int kt = 0; kt < 2; ++kt)
            qf[mt][kt] = *(const short8*)&qb[(mt * 16 + l15) * DHEAD + kt * 32 + q8];

    float4v of[2][4];
#pragma unroll
    for (int mt = 0; mt < 2; ++mt)
#pragma unroll
        for (int dt = 0; dt < 4; ++dt) of[mt][dt] = (float4v){0.f, 0.f, 0.f, 0.f};
    float l_acc[2][4];
#pragma unroll
    for (int mt = 0; mt < 2; ++mt)
#pragma unroll
        for (int r = 0; r < 4; ++r) l_acc[mt][r] = 0.f;

    const short* kbase = (const short*)kh + (size_t)bh * NSEQ * DHEAD;
    const short* vbase = (const short*)vb + (size_t)bh * DHEAD * NSEQ;

    const int jlo = z * (NSEQ / 2), jhi = jlo + NSEQ / 2;
    for (int j0 = jlo; j0 < jhi; j0 += 64) {
#pragma unroll
        for (int it = 0; it < 2; ++it) {
            int row = it * 32 + (tid >> 3);
            cp16(kbase + (size_t)(j0 + row) * DHEAD + cswz, &Kt[it * 2048 + wave * 512]);
            cp16(vbase + (size_t)row * NSEQ + j0 + cswz, &Vt[it * 2048 + wave * 512]);
        }
        __syncthreads();

        float4v s[2][4];
#pragma unroll
        for (int nt = 0; nt < 4; ++nt) {
            short8 kf0 = *(const short8*)&Kt[(nt * 16 + l15) * 64 + ((0 * 4 + quad) ^ sw7) * 8];
            short8 kf1 = *(const short8*)&Kt[(nt * 16 + l15) * 64 + ((1 * 4 + quad) ^ sw7) * 8];
#pragma unroll
            for (int mt = 0; mt < 2; ++mt) {
                float4v zz = mInit;   // C-init = -M2: free bias, no VALU sub
                zz = __builtin_amdgcn_mfma_f32_16x16x32_bf16(qf[mt][0], kf0, zz, 0, 0, 0);
                zz = __builtin_amdgcn_mfma_f32_16x16x32_bf16(qf[mt][1], kf1, zz, 0, 0, 0);
                s[mt][nt] = zz;
            }
        }

#pragma unroll
        for (int mt = 0; mt < 2; ++mt)
#pragma unroll
            for (int r = 0; r < 4; ++r) {
                int prow = wave * 32 + mt * 16 + quad * 4 + r;
                int psw = (prow & 7);
                float p0 = fexp2(s[mt][0][r]);
                float p1 = fexp2(s[mt][1][r]);
                float p2 = fexp2(s[mt][2][r]);
                float p3 = fexp2(s[mt][3][r]);
                l_acc[mt][r] += (p0 + p1) + (p2 + p3);
                Pt[prow * 64 + (((0 * 2 + (l15 >> 3)) ^ psw) * 8) + (l15 & 7)] = (short)f2bf_fast(p0);
                Pt[prow * 64 + (((1 * 2 + (l15 >> 3)) ^ psw) * 8) + (l15 & 7)] = (short)f2bf_fast(p1);
                Pt[prow * 64 + (((2 * 2 + (l15 >> 3)) ^ psw) * 8) + (l15 & 7)] = (short)f2bf_fast(p2);
                Pt[prow * 64 + (((3 * 2 + (l15 >> 3)) ^ psw) * 8) + (l15 & 7)] = (short)f2bf_fast(p3);
            }
        __syncthreads();

#pragma unroll
        for (int mt = 0; mt < 2; ++mt) {
            int arow = wave * 32 + mt * 16 + l15;
            short8 af0 = *(const short8*)&Pt[arow * 64 + ((0 * 4 + quad) ^ sw7) * 8];
            short8 af1 = *(const short8*)&Pt[arow * 64 + ((1 * 4 + quad) ^ sw7) * 8];
#pragma unroll
            for (int dt = 0; dt < 4; ++dt) {
                short8 vf0 = *(const short8*)&Vt[(dt * 16 + l15) * 64 + ((0 * 4 + quad) ^ sw7) * 8];
                short8 vf1 = *(const short8*)&Vt[(dt * 16 + l15) * 64 + ((1 * 4 + quad) ^ sw7) * 8];
                of[mt][dt] = __builtin_amdgcn_mfma_f32_16x16x32_bf16(af0, vf0, of[mt][dt], 0, 0, 0);
                of[mt][dt] = __builtin_amdgcn_mfma_f32_16x16x32_bf16(af1, vf1, of[mt][dt], 0, 0, 0);
            }
        }
        __syncthreads();
    }

#pragma unroll
    for (int mt = 0; mt < 2; ++mt)
#pragma unroll
        for (int r = 0; r < 4; ++r) {
            float l = l_acc[mt][r];
#pragma unroll
            for (int off = 1; off < 16; off <<= 1) l += __shfl_xor(l, off);
            l_acc[mt][r] = l;
        }

    float* ob = opart + ((size_t)(z * 32 + bh) * NSEQ) * DHEAD;
    float* lb = lpart + (size_t)(z * 32 + bh) * NSEQ;
#pragma unroll
    for (int mt = 0; mt < 2; ++mt) {
#pragma unroll
        for (int dt = 0; dt < 4; ++dt)
#pragma unroll
            for (int r = 0; r < 4; ++r) {
                int i = i0 + wave * 32 + mt * 16 + quad * 4 + r;
                ob[(size_t)i * DHEAD + dt * 16 + l15] = of[mt][dt][r];
            }
        if (l15 == 0)
#pragma unroll
            for (int r = 0; r < 4; ++r)
                lb[i0 + wave * 32 + mt * 16 + quad * 4 + r] = l_acc[mt][r];
    }
}

// ---------------------------------------------------------------------------
// k_merge: o = (o0+o1)/(l0+l1) -> aot bf16 [b][n][h*64+d]
// ---------------------------------------------------------------------------
__global__ __launch_bounds__(256) void k_merge(
    const float* __restrict__ opart, const float* __restrict__ lpart,
    unsigned short* __restrict__ aot) {
    int t = blockIdx.x * 256 + threadIdx.x;
    int bh = t >> 15, rem = t & 32767;
    int i = rem >> 4, d = (rem & 15) * 4;
    size_t row = (size_t)bh * NSEQ + i;
    const float* o0 = opart;
    const float* o1 = opart + (size_t)32 * NSEQ * DHEAD;
    float l = lpart[row] + lpart[(size_t)32 * NSEQ + row];
    float inv = 1.0f / fmaxf(l, 1e-30f);
    float4 a = *(const float4*)(o0 + row * DHEAD + d);
    float4 b = *(const float4*)(o1 + row * DHEAD + d);
    ushort4 o;
    o.x = f2bf((a.x + b.x) * inv); o.y = f2bf((a.y + b.y) * inv);
    o.z = f2bf((a.z + b.z) * inv); o.w = f2bf((a.w + b.w) * inv);
    int bb = bh >> 4, h = bh & 15;
    *(ushort4*)(aot + ((size_t)bb * NSEQ + i) * HDIM + h * DHEAD + d) = o;
}

// ---------------------------------------------------------------------------
// k_gemm_out: y[b][o][n] f32 = sum_c Wout[o][c]*aot[b][n][c] + bout[o]
// ---------------------------------------------------------------------------
__global__ __launch_bounds__(256) void k_gemm_out(
    const unsigned short* __restrict__ W, const unsigned short* __restrict__ aot,
    const float* __restrict__ bias, float* __restrict__ out) {
    constexpr int K = HDIM, N = NSEQ, M = CCH;
    __shared__ __align__(16) short lsA[64 * 64];
    __shared__ __align__(16) short lsB[64 * 64];
    const int tid = threadIdx.x, wave = tid >> 6, lane = tid & 63;
    const int l15 = lane & 15, quad = lane >> 4;
    const int n0 = blockIdx.x * 64, m0 = blockIdx.y * 64, z = blockIdx.z;
    const short* Ab = (const short*)W + (size_t)m0 * K;
    const short* Bb = (const short*)aot + ((size_t)z * N + n0) * K;
    const int wm = wave >> 1, wn = wave & 1;
    const int cswz = (((tid & 7) ^ ((tid >> 3) & 7))) * 8;
    const int sw7 = (l15 & 7);

    float4v acc[2][2];
#pragma unroll
    for (int i = 0; i < 2; ++i)
#pragma unroll
        for (int j = 0; j < 2; ++j) acc[i][j] = (float4v){0.f, 0.f, 0.f, 0.f};

    for (int k0 = 0; k0 < K; k0 += 64) {
        {
            int row = tid >> 3;
            cp16(Ab + (size_t)row * K + k0 + cswz, &lsA[wave * 512]);
            cp16(Ab + (size_t)(row + 32) * K + k0 + cswz, &lsA[2048 + wave * 512]);
            cp16(Bb + (size_t)row * K + k0 + cswz, &lsB[wave * 512]);
            cp16(Bb + (size_t)(row + 32) * K + k0 + cswz, &lsB[2048 + wave * 512]);
        }
        __syncthreads();
        short8 af[2][2], bfr[2][2];
#pragma unroll
        for (int t = 0; t < 2; ++t)
#pragma unroll
            for (int kk = 0; kk < 2; ++kk) {
                af[t][kk]  = *(const short8*)&lsA[(wm * 32 + t * 16 + l15) * 64 + ((kk * 4 + quad) ^ sw7) * 8];
                bfr[t][kk] = *(const short8*)&lsB[(wn * 32 + t * 16 + l15) * 64 + ((kk * 4 + quad) ^ sw7) * 8];
            }
#pragma unroll
        for (int mt = 0; mt < 2; ++mt)
#pragma unroll
            for (int nt = 0; nt < 2; ++nt) {
                acc[mt][nt] = __builtin_amdgcn_mfma_f32_16x16x32_bf16(af[mt][0], bfr[nt][0], acc[mt][nt], 0, 0, 0);
                acc[mt][nt] = __builtin_amdgcn_mfma_f32_16x16x32_bf16(af[mt][1], bfr[nt][1], acc[mt][nt], 0, 0, 0);
            }
        __syncthreads();
    }
    float* Co = out + (size_t)z * M * N;
#pragma unroll
    for (int mt = 0; mt < 2; ++mt)
#pragma unroll
        for (int nt = 0; nt < 2; ++nt) {
            int mrow = m0 + wm * 32 + mt * 16 + quad * 4;
#pragma unroll
            for (int r = 0; r < 4; ++r) {
                int mr = mrow + r;
                int nc = n0 + wn * 32 + nt * 16 + l15;
                Co[(size_t)mr * N + nc] = acc[mt][nt][r] + bias[mr];
            }
        }
}

// ---------------------------------------------------------------------------
// Launch.  Inputs resolved by element count (f32).
// ---------------------------------------------------------------------------
extern "C" void kernel_launch(void* const* d_in, const int* in_sizes, int n_in,
                              void* d_out, int out_size, void* d_ws, size_t ws_size,
                              hipStream_t stream) {
    const float* x = nullptr; const float* Wqkv = nullptr;
    const float* qs = nullptr; const float* ks = nullptr;
    const float* Wout = nullptr; const float* bout = nullptr;
    for (int i = 0; i < n_in; ++i) {
        switch (in_sizes[i]) {
            case BATCH * CCH * NSEQ: x    = (const float*)d_in[i]; break;
            case ODIM * CCH:         Wqkv = (const float*)d_in[i]; break;
            case CCH * HDIM:         Wout = (const float*)d_in[i]; break;
            case CCH:                bout = (const float*)d_in[i]; break;
            case DHEAD: if (!qs) qs = (const float*)d_in[i]; else ks = (const float*)d_in[i]; break;
            default: break;
        }
    }
    float* y = (float*)d_out;

    char* ws = (char*)d_ws;
    float*          Mbuf  = (float*)(ws + 0);
    unsigned short* Wqkvb = (unsigned short*)(ws + 4096);        // 3,145,728 B
    unsigned short* Woutb = (unsigned short*)(ws + 3149824);     // 1,048,576 B
    unsigned short* xt    = (unsigned short*)(ws + 4198400);     // 4,194,304 B
    unsigned short* qh    = (unsigned short*)(ws + 8392704);     // 8,388,608 B
    unsigned short* kh    = (unsigned short*)(ws + 16781312);    // 8,388,608 B
    unsigned short* vb    = (unsigned short*)(ws + 25169920);    // 8,388,608 B
    unsigned short* aot   = (unsigned short*)(ws + 33558528);    // 8,388,608 B
    float*          opart = (float*)(ws + 41947136);             // 33,554,432 B
    float*          lpart = (float*)(ws + 75501568);             //    524,288 B -> 76,025,856

    k_convert_w<<<(ODIM * CCH + CCH * HDIM) / 4 / 256, 256, 0, stream>>>(
        Wqkv, Wout, qs, ks, Wqkvb, Woutb, Mbuf);
    k_transpose_x<<<dim3(NSEQ / 64, CCH / 64, BATCH), 256, 0, stream>>>(x, xt);
    k_gemm_qkv<<<dim3(NSEQ / 128, ODIM / 128, BATCH), 256, 0, stream>>>(Wqkvb, xt, qs, ks, qh, kh, vb);
    k_attn<<<dim3(1024), 256, 0, stream>>>(qh, kh, vb, opart, lpart, Mbuf);
    k_merge<<<dim3(BATCH * HEADS * NSEQ * (DHEAD / 4) / 256), 256, 0, stream>>>(opart, lpart, aot);
    k_gemm_out<<<dim3(NSEQ / 64, CCH / 64, BATCH), 256, 0, stream>>>(Woutb, aot, bout, y);
}

// Round 8
// 170.964 us; speedup vs baseline: 1.0340x; 1.0340x over previous
//
#include <hip/hip_runtime.h>
#include <hip/hip_bf16.h>

// ---------------------------------------------------------------------------
// Problem constants.  Inputs f32, output f32 (proven R4).
// ---------------------------------------------------------------------------
#define BATCH 2
#define CCH   512
#define NSEQ  2048
#define HEADS 16
#define DHEAD 64
#define HDIM  1024
#define ODIM  3072
// 8 * log2(e): folded into q-hat at the GEMM epilogue; M2 = this * max|qs*ks|.
#define QK_PRESCALE 11.541560327111707f

typedef short short4v __attribute__((ext_vector_type(4)));
typedef short short8 __attribute__((ext_vector_type(8)));
typedef float float4v __attribute__((ext_vector_type(4)));

__device__ __forceinline__ unsigned short f2bf(float f) {          // RNE
    unsigned int u = __float_as_uint(f);
    return (unsigned short)((u + 0x7FFFu + ((u >> 16) & 1u)) >> 16);
}
__device__ __forceinline__ unsigned short f2bf_fast(float f) {     // round-half-up
    return (unsigned short)((__float_as_uint(f) + 0x8000u) >> 16);
}
__device__ __forceinline__ float fexp2(float x) {
#if __has_builtin(__builtin_amdgcn_exp2f)
    return __builtin_amdgcn_exp2f(x);
#else
    return exp2f(x);
#endif
}

typedef __attribute__((address_space(1))) const void* as1_cvp;
typedef __attribute__((address_space(3))) void* as3_vp;
__device__ __forceinline__ void cp16(const void* g, void* l) {
    __builtin_amdgcn_global_load_lds((as1_cvp)g, (as3_vp)l, 16, 0, 0);
}
// LDS XOR swizzle (R5, verified: SQ_LDS_BANK_CONFLICT -> 0): slot (row,chunk)
// holds global (row, chunk ^ (row&7)); staging lane fetches global chunk
// (tid&7)^((tid>>3)&7).

// ---------------------------------------------------------------------------
// k_convert_w: f32 -> bf16 for Wqkv then Wout; block 0 also computes
// M2 = QK_PRESCALE * max_d |qs_d*ks_d| (exact softmax bound, Cauchy-Schwarz).
// ---------------------------------------------------------------------------
__global__ __launch_bounds__(256) void k_convert_w(
    const float* __restrict__ Wqkv, const float* __restrict__ Wout,
    const float* __restrict__ qs, const float* __restrict__ ks,
    unsigned short* __restrict__ Wqkvb, unsigned short* __restrict__ Woutb,
    float* __restrict__ M) {
    if (blockIdx.x == 0 && threadIdx.x < 64) {
        int lane = threadIdx.x;
        float p = fabsf(qs[lane] * ks[lane]);
#pragma unroll
        for (int off = 1; off < 64; off <<= 1) p = fmaxf(p, __shfl_xor(p, off));
        if (lane == 0) *M = QK_PRESCALE * p;
    }
    int i4 = (blockIdx.x * 256 + threadIdx.x) * 4;
    const float* src; unsigned short* dst; int idx;
    if (i4 < ODIM * CCH) { src = Wqkv; dst = Wqkvb; idx = i4; }
    else { src = Wout; dst = Woutb; idx = i4 - ODIM * CCH; }
    float4 v = *(const float4*)(src + idx);
    ushort4 o;
    o.x = f2bf(v.x); o.y = f2bf(v.y); o.z = f2bf(v.z); o.w = f2bf(v.w);
    *(ushort4*)(dst + idx) = o;
}

// ---------------------------------------------------------------------------
// k_transpose_x: x [b][c][n] f32 -> xt [b][n][c] bf16
// ---------------------------------------------------------------------------
__global__ __launch_bounds__(256) void k_transpose_x(
    const float* __restrict__ x, unsigned short* __restrict__ xt) {
    __shared__ unsigned short t[64][65];
    const int b = blockIdx.z, c0 = blockIdx.y * 64, n0 = blockIdx.x * 64;
    const int tr = threadIdx.x >> 6, tc = threadIdx.x & 63;
    const float* xs = x + (size_t)b * CCH * NSEQ;
    unsigned short* xd = xt + (size_t)b * NSEQ * CCH;
#pragma unroll
    for (int r = 0; r < 16; ++r) {
        int c = r * 4 + tr;
        t[c][tc] = f2bf(xs[(size_t)(c0 + c) * NSEQ + n0 + tc]);
    }
    __syncthreads();
#pragma unroll
    for (int r = 0; r < 16; ++r) {
        int n = r * 4 + tr;
        xd[(size_t)(n0 + n) * CCH + c0 + tc] = t[tc][n];
    }
}

// ---------------------------------------------------------------------------
// k_gemm_qkv: fused QKV GEMM + l2-norm/scale + head repack (R7 epilogue:
// per-wave LDS transpose, 128B-row global stores).
//   q (part0): qh[bh][n][d] bf16, pre-scaled by QK_PRESCALE
//   k (part1): kh[bh][n][d] bf16
//   v (part2): vb[bh][d][n] bf16
// ---------------------------------------------------------------------------
__global__ __launch_bounds__(256) void k_gemm_qkv(
    const unsigned short* __restrict__ W, const unsigned short* __restrict__ xt,
    const float* __restrict__ qs, const float* __restrict__ ks,
    unsigned short* __restrict__ qh, unsigned short* __restrict__ kh,
    unsigned short* __restrict__ vb) {
    constexpr int K = CCH, N = NSEQ;
    __shared__ __align__(16) short smem[2 * 128 * 64];
    short* lsA = smem;
    short* lsB = smem + 128 * 64;
    const int tid = threadIdx.x, wave = tid >> 6, lane = tid & 63;
    const int l15 = lane & 15, quad = lane >> 4;
    const int n0 = blockIdx.x * 128, m0 = blockIdx.y * 128, z = blockIdx.z;
    const short* Ab = (const short*)W + (size_t)m0 * K;
    const short* Bb = (const short*)xt + ((size_t)z * N + n0) * K;
    const int wm = wave >> 1, wn = wave & 1;
    const int cswz = (((tid & 7) ^ ((tid >> 3) & 7))) * 8;
    const int sw7 = (l15 & 7);

    float4v acc[4][4];
#pragma unroll
    for (int i = 0; i < 4; ++i)
#pragma unroll
        for (int j = 0; j < 4; ++j) acc[i][j] = (float4v){0.f, 0.f, 0.f, 0.f};

    for (int k0 = 0; k0 < K; k0 += 64) {
#pragma unroll
        for (int it = 0; it < 4; ++it) {
            int row = it * 32 + (tid >> 3);
            cp16(Ab + (size_t)row * K + k0 + cswz, &lsA[it * 2048 + wave * 512]);
            cp16(Bb + (size_t)row * K + k0 + cswz, &lsB[it * 2048 + wave * 512]);
        }
        __syncthreads();
        short8 af[4][2], bfr[4][2];
#pragma unroll
        for (int t = 0; t < 4; ++t)
#pragma unroll
            for (int kk = 0; kk < 2; ++kk) {
                af[t][kk]  = *(const short8*)&lsA[(wm * 64 + t * 16 + l15) * 64 + ((kk * 4 + quad) ^ sw7) * 8];
                bfr[t][kk] = *(const short8*)&lsB[(wn * 64 + t * 16 + l15) * 64 + ((kk * 4 + quad) ^ sw7) * 8];
            }
#pragma unroll
        for (int mt = 0; mt < 4; ++mt)
#pragma unroll
            for (int nt = 0; nt < 4; ++nt) {
                acc[mt][nt] = __builtin_amdgcn_mfma_f32_16x16x32_bf16(af[mt][0], bfr[nt][0], acc[mt][nt], 0, 0, 0);
                acc[mt][nt] = __builtin_amdgcn_mfma_f32_16x16x32_bf16(af[mt][1], bfr[nt][1], acc[mt][nt], 0, 0, 0);
            }
        __syncthreads();
    }

    // ---- fused epilogue (per-wave 8KB LDS scratch; intra-wave, no barrier) --
    const int co   = (m0 + wm * 64) >> 6;
    const int part = co >> 4;               // 0=q, 1=k, 2=v
    const int h    = co & 15;
    const int bh   = z * HEADS + h;
    short* myT = smem + wave * 4096;

    if (part < 2) {
        float inv[4];
#pragma unroll
        for (int nt = 0; nt < 4; ++nt) {
            float ss = 0.f;
#pragma unroll
            for (int mt = 0; mt < 4; ++mt)
#pragma unroll
                for (int r = 0; r < 4; ++r) ss += acc[mt][nt][r] * acc[mt][nt][r];
            ss += __shfl_xor(ss, 16);
            ss += __shfl_xor(ss, 32);
            inv[nt] = 1.0f / fmaxf(sqrtf(ss), 1e-12f);
        }
        const float* sc = part ? ks : qs;
        const float csc = part ? 1.0f : QK_PRESCALE;
#pragma unroll
        for (int mt = 0; mt < 4; ++mt) {
            const int db = mt * 16 + quad * 4;
            float4 s4 = *(const float4*)(sc + db);
            s4.x *= csc; s4.y *= csc; s4.z *= csc; s4.w *= csc;
#pragma unroll
            for (int nt = 0; nt < 4; ++nt) {
                int nl = nt * 16 + l15;
                short4v o;
                o.x = (short)f2bf(acc[mt][nt][0] * inv[nt] * s4.x);
                o.y = (short)f2bf(acc[mt][nt][1] * inv[nt] * s4.y);
                o.z = (short)f2bf(acc[mt][nt][2] * inv[nt] * s4.z);
                o.w = (short)f2bf(acc[mt][nt][3] * inv[nt] * s4.w);
                *(short4v*)&myT[nl * 64 + (((db >> 3) ^ (nl & 7)) << 3) + (db & 7)] = o;
            }
        }
        unsigned short* dst = (part ? kh : qh) + (size_t)bh * NSEQ * DHEAD
                              + (size_t)(n0 + wn * 64) * DHEAD;
#pragma unroll
        for (int pass = 0; pass < 8; ++pass) {
            int nl = pass * 8 + (lane >> 3), c = lane & 7;
            short8 vv = *(const short8*)&myT[nl * 64 + ((c ^ (nl & 7)) << 3)];
            *(short8*)&dst[(size_t)nl * DHEAD + c * 8] = vv;
        }
    } else {
#pragma unroll
        for (int mt = 0; mt < 4; ++mt)
#pragma unroll
            for (int nt = 0; nt < 4; ++nt) {
                int nl = nt * 16 + l15;
                int swc = nl >> 3, swo = nl & 7;
#pragma unroll
                for (int r = 0; r < 4; ++r) {
                    int d = mt * 16 + quad * 4 + r;
                    myT[d * 64 + ((swc ^ (d & 7)) << 3) + swo] = (short)f2bf(acc[mt][nt][r]);
                }
            }
        unsigned short* dst = vb + (size_t)bh * DHEAD * NSEQ + n0 + wn * 64;
#pragma unroll
        for (int pass = 0; pass < 8; ++pass) {
            int d = pass * 8 + (lane >> 3), c = lane & 7;
            short8 vv = *(const short8*)&myT[d * 64 + ((c ^ (d & 7)) << 3)];
            *(short8*)&dst[(size_t)d * NSEQ + c * 8] = vv;
        }
    }
}

// ---------------------------------------------------------------------------
// k_attn v2: i-tile 64, full j-loop per block (no partials/merge).
// Double-buffered K/V staging, ONE barrier per j-tile (Pt is intra-wave:
// wave writes rows [wave*16,wave*16+16) and PV reads exactly those rows).
// q pre-scaled by 8*log2e, MFMA C-init = -M2  =>  p = exp2(s), 1 VALU op.
// Writes normalized bf16 aot[b][n][h*64+d] directly.
// ---------------------------------------------------------------------------
__global__ __launch_bounds__(256, 4) void k_attn(
    const unsigned short* __restrict__ qh, const unsigned short* __restrict__ kh,
    const unsigned short* __restrict__ vb,
    unsigned short* __restrict__ aot, const float* __restrict__ Mptr) {
    __shared__ __align__(16) short Kt[2][64 * 64];
    __shared__ __align__(16) short Vt[2][64 * 64];
    __shared__ __align__(16) short Pt[64 * 64];
    const int tid = threadIdx.x, wave = tid >> 6, lane = tid & 63;
    const int l15 = lane & 15, quad = lane >> 4, q8 = quad * 8;
    // XCD-local decode: 4 bh per XCD, 32 i-blocks each (KV slab 1MB -> L2-resident)
    const int flat = blockIdx.x;
    const int xcd = flat & 7, idx = flat >> 3;
    const int bh = xcd * 4 + (idx >> 5);
    const int i0 = (idx & 31) * 64;
    const int b = bh >> 4, h = bh & 15;
    const float Ms = *Mptr;
    const float4v mInit = (float4v){-Ms, -Ms, -Ms, -Ms};
    const int cswz = (((tid & 7) ^ ((tid >> 3) & 7))) * 8;
    const int sw7 = (l15 & 7);
    const int srow = tid >> 3;   // staging row 0..31

    // Q fragments: wave owns rows [i0+wave*16, +16)
    short8 qf[2];
    {
        const short* qb = (const short*)qh + ((size_t)bh * NSEQ + i0 + wave * 16) * DHEAD;
        qf[0] = *(const short8*)&qb[l15 * DHEAD + q8];
        qf[1] = *(const short8*)&qb[l15 * DHEAD + 32 + q8];
    }

    float4v of[4];
#pragma unroll
    for (int dt = 0; dt < 4; ++dt) of[dt] = (float4v){0.f, 0.f, 0.f, 0.f};
    float l_acc[4] = {0.f, 0.f, 0.f, 0.f};

    const short* kbase = (const short*)kh + (size_t)bh * NSEQ * DHEAD;
    const short* vbase = (const short*)vb + (size_t)bh * DHEAD * NSEQ;
    short* myP = Pt + wave * 1024;   // 16 x 64

    // prologue: stage tile j=0 into buf 0
#pragma unroll
    for (int it = 0; it < 2; ++it) {
        int row = it * 32 + srow;
        cp16(kbase + (size_t)row * DHEAD + cswz, &Kt[0][it * 2048 + wave * 512]);
        cp16(vbase + (size_t)row * NSEQ + cswz, &Vt[0][it * 2048 + wave * 512]);
    }
    __syncthreads();

    int buf = 0;
    for (int j0 = 0; j0 < NSEQ; j0 += 64) {
        // stage next tile into buf^1 (in flight across this tile's compute)
        if (j0 + 64 < NSEQ) {
            int nb = buf ^ 1;
#pragma unroll
            for (int it = 0; it < 2; ++it) {
                int row = it * 32 + srow;
                cp16(kbase + (size_t)(j0 + 64 + row) * DHEAD + cswz, &Kt[nb][it * 2048 + wave * 512]);
                cp16(vbase + (size_t)row * NSEQ + j0 + 64 + cswz, &Vt[nb][it * 2048 + wave * 512]);
            }
        }

        // S = Q K^T  (C-init = -M2)
        float4v s[4];
#pragma unroll
        for (int nt = 0; nt < 4; ++nt) {
            short8 kf0 = *(const short8*)&Kt[buf][(nt * 16 + l15) * 64 + ((0 + quad) ^ sw7) * 8];
            short8 kf1 = *(const short8*)&Kt[buf][(nt * 16 + l15) * 64 + ((4 + quad) ^ sw7) * 8];
            float4v zz = mInit;
            zz = __builtin_amdgcn_mfma_f32_16x16x32_bf16(qf[0], kf0, zz, 0, 0, 0);
            zz = __builtin_amdgcn_mfma_f32_16x16x32_bf16(qf[1], kf1, zz, 0, 0, 0);
            s[nt] = zz;
        }

        // softmax: p = exp2(s); Pt store swizzled (intra-wave region)
#pragma unroll
        for (int r = 0; r < 4; ++r) {
            int prow = quad * 4 + r;
            int psw = prow & 7;
            float p0 = fexp2(s[0][r]);
            float p1 = fexp2(s[1][r]);
            float p2 = fexp2(s[2][r]);
            float p3 = fexp2(s[3][r]);
            l_acc[r] += (p0 + p1) + (p2 + p3);
            myP[prow * 64 + (((0 + (l15 >> 3)) ^ psw) * 8) + (l15 & 7)] = (short)f2bf_fast(p0);
            myP[prow * 64 + (((2 + (l15 >> 3)) ^ psw) * 8) + (l15 & 7)] = (short)f2bf_fast(p1);
            myP[prow * 64 + (((4 + (l15 >> 3)) ^ psw) * 8) + (l15 & 7)] = (short)f2bf_fast(p2);
            myP[prow * 64 + (((6 + (l15 >> 3)) ^ psw) * 8) + (l15 & 7)] = (short)f2bf_fast(p3);
        }
        // NO barrier: Pt producer==consumer wave (lgkmcnt ordering suffices)

        // O += P V
        short8 af0 = *(const short8*)&myP[l15 * 64 + ((0 + quad) ^ sw7) * 8];
        short8 af1 = *(const short8*)&myP[l15 * 64 + ((4 + quad) ^ sw7) * 8];
#pragma unroll
        for (int dt = 0; dt < 4; ++dt) {
            short8 vf0 = *(const short8*)&Vt[buf][(dt * 16 + l15) * 64 + ((0 + quad) ^ sw7) * 8];
            short8 vf1 = *(const short8*)&Vt[buf][(dt * 16 + l15) * 64 + ((4 + quad) ^ sw7) * 8];
            of[dt] = __builtin_amdgcn_mfma_f32_16x16x32_bf16(af0, vf0, of[dt], 0, 0, 0);
            of[dt] = __builtin_amdgcn_mfma_f32_16x16x32_bf16(af1, vf1, of[dt], 0, 0, 0);
        }

        __syncthreads();   // next buf staged (vmcnt drain) + this buf consumed
        buf ^= 1;
    }

    // normalize l over the 16 lanes sharing each row
#pragma unroll
    for (int r = 0; r < 4; ++r) {
        float l = l_acc[r];
        l += __shfl_xor(l, 1); l += __shfl_xor(l, 2);
        l += __shfl_xor(l, 4); l += __shfl_xor(l, 8);
        l_acc[r] = 1.0f / fmaxf(l, 1e-30f);
    }

    unsigned short* ob = aot + ((size_t)b * NSEQ + i0 + wave * 16) * HDIM + h * DHEAD;
#pragma unroll
    for (int dt = 0; dt < 4; ++dt)
#pragma unroll
        for (int r = 0; r < 4; ++r)
            ob[(size_t)(quad * 4 + r) * HDIM + dt * 16 + l15] = f2bf(of[dt][r] * l_acc[r]);
}

// ---------------------------------------------------------------------------
// k_gemm_out: y[b][o][n] f32 = sum_c Wout[o][c]*aot[b][n][c] + bout[o]
// ---------------------------------------------------------------------------
__global__ __launch_bounds__(256) void k_gemm_out(
    const unsigned short* __restrict__ W, const unsigned short* __restrict__ aot,
    const float* __restrict__ bias, float* __restrict__ out) {
    constexpr int K = HDIM, N = NSEQ, M = CCH;
    __shared__ __align__(16) short lsA[64 * 64];
    __shared__ __align__(16) short lsB[64 * 64];
    const int tid = threadIdx.x, wave = tid >> 6, lane = tid & 63;
    const int l15 = lane & 15, quad = lane >> 4;
    const int n0 = blockIdx.x * 64, m0 = blockIdx.y * 64, z = blockIdx.z;
    const short* Ab = (const short*)W + (size_t)m0 * K;
    const short* Bb = (const short*)aot + ((size_t)z * N + n0) * K;
    const int wm = wave >> 1, wn = wave & 1;
    const int cswz = (((tid & 7) ^ ((tid >> 3) & 7))) * 8;
    const int sw7 = (l15 & 7);

    float4v acc[2][2];
#pragma unroll
    for (int i = 0; i < 2; ++i)
#pragma unroll
        for (int j = 0; j < 2; ++j) acc[i][j] = (float4v){0.f, 0.f, 0.f, 0.f};

    for (int k0 = 0; k0 < K; k0 += 64) {
        {
            int row = tid >> 3;
            cp16(Ab + (size_t)row * K + k0 + cswz, &lsA[wave * 512]);
            cp16(Ab + (size_t)(row + 32) * K + k0 + cswz, &lsA[2048 + wave * 512]);
            cp16(Bb + (size_t)row * K + k0 + cswz, &lsB[wave * 512]);
            cp16(Bb + (size_t)(row + 32) * K + k0 + cswz, &lsB[2048 + wave * 512]);
        }
        __syncthreads();
        short8 af[2][2], bfr[2][2];
#pragma unroll
        for (int t = 0; t < 2; ++t)
#pragma unroll
            for (int kk = 0; kk < 2; ++kk) {
                af[t][kk]  = *(const short8*)&lsA[(wm * 32 + t * 16 + l15) * 64 + ((kk * 4 + quad) ^ sw7) * 8];
                bfr[t][kk] = *(const short8*)&lsB[(wn * 32 + t * 16 + l15) * 64 + ((kk * 4 + quad) ^ sw7) * 8];
            }
#pragma unroll
        for (int mt = 0; mt < 2; ++mt)
#pragma unroll
            for (int nt = 0; nt < 2; ++nt) {
                acc[mt][nt] = __builtin_amdgcn_mfma_f32_16x16x32_bf16(af[mt][0], bfr[nt][0], acc[mt][nt], 0, 0, 0);
                acc[mt][nt] = __builtin_amdgcn_mfma_f32_16x16x32_bf16(af[mt][1], bfr[nt][1], acc[mt][nt], 0, 0, 0);
            }
        __syncthreads();
    }
    float* Co = out + (size_t)z * M * N;
#pragma unroll
    for (int mt = 0; mt < 2; ++mt)
#pragma unroll
        for (int nt = 0; nt < 2; ++nt) {
            int mrow = m0 + wm * 32 + mt * 16 + quad * 4;
#pragma unroll
            for (int r = 0; r < 4; ++r) {
                int mr = mrow + r;
                int nc = n0 + wn * 32 + nt * 16 + l15;
                Co[(size_t)mr * N + nc] = acc[mt][nt][r] + bias[mr];
            }
        }
}

// ---------------------------------------------------------------------------
// Launch.  Inputs resolved by element count (f32).
// ---------------------------------------------------------------------------
extern "C" void kernel_launch(void* const* d_in, const int* in_sizes, int n_in,
                              void* d_out, int out_size, void* d_ws, size_t ws_size,
                              hipStream_t stream) {
    const float* x = nullptr; const float* Wqkv = nullptr;
    const float* qs = nullptr; const float* ks = nullptr;
    const float* Wout = nullptr; const float* bout = nullptr;
    for (int i = 0; i < n_in; ++i) {
        switch (in_sizes[i]) {
            case BATCH * CCH * NSEQ: x    = (const float*)d_in[i]; break;
            case ODIM * CCH:         Wqkv = (const float*)d_in[i]; break;
            case CCH * HDIM:         Wout = (const float*)d_in[i]; break;
            case CCH:                bout = (const float*)d_in[i]; break;
            case DHEAD: if (!qs) qs = (const float*)d_in[i]; else ks = (const float*)d_in[i]; break;
            default: break;
        }
    }
    float* y = (float*)d_out;

    char* ws = (char*)d_ws;
    float*          Mbuf  = (float*)(ws + 0);
    unsigned short* Wqkvb = (unsigned short*)(ws + 4096);        // 3,145,728 B
    unsigned short* Woutb = (unsigned short*)(ws + 3149824);     // 1,048,576 B
    unsigned short* xt    = (unsigned short*)(ws + 4198400);     // 4,194,304 B
    unsigned short* qh    = (unsigned short*)(ws + 8392704);     // 8,388,608 B
    unsigned short* kh    = (unsigned short*)(ws + 16781312);    // 8,388,608 B
    unsigned short* vb    = (unsigned short*)(ws + 25169920);    // 8,388,608 B
    unsigned short* aot   = (unsigned short*)(ws + 33558528);    // 8,388,608 B -> 41,947,136

    k_convert_w<<<(ODIM * CCH + CCH * HDIM) / 4 / 256, 256, 0, stream>>>(
        Wqkv, Wout, qs, ks, Wqkvb, Woutb, Mbuf);
    k_transpose_x<<<dim3(NSEQ / 64, CCH / 64, BATCH), 256, 0, stream>>>(x, xt);
    k_gemm_qkv<<<dim3(NSEQ / 128, ODIM / 128, BATCH), 256, 0, stream>>>(Wqkvb, xt, qs, ks, qh, kh, vb);
    k_attn<<<dim3(1024), 256, 0, stream>>>(qh, kh, vb, aot, Mbuf);
    k_gemm_out<<<dim3(NSEQ / 64, CCH / 64, BATCH), 256, 0, stream>>>(Woutb, aot, bout, y);
}

// Round 9
// 161.364 us; speedup vs baseline: 1.0955x; 1.0595x over previous
//
#include <hip/hip_runtime.h>
#include <hip/hip_bf16.h>

// ---------------------------------------------------------------------------
// Problem constants.  Inputs f32, output f32 (proven R4).
// ---------------------------------------------------------------------------
#define BATCH 2
#define CCH   512
#define NSEQ  2048
#define HEADS 16
#define DHEAD 64
#define HDIM  1024
#define ODIM  3072
// 8 * log2(e): folded into q-hat at the GEMM epilogue; M2 = this * max|qs*ks|.
#define QK_PRESCALE 11.541560327111707f

typedef short short4v __attribute__((ext_vector_type(4)));
typedef short short8 __attribute__((ext_vector_type(8)));
typedef float float4v __attribute__((ext_vector_type(4)));

__device__ __forceinline__ unsigned short f2bf(float f) {          // RNE
    unsigned int u = __float_as_uint(f);
    return (unsigned short)((u + 0x7FFFu + ((u >> 16) & 1u)) >> 16);
}
__device__ __forceinline__ unsigned short f2bf_fast(float f) {     // round-half-up
    return (unsigned short)((__float_as_uint(f) + 0x8000u) >> 16);
}
__device__ __forceinline__ float fexp2(float x) {
#if __has_builtin(__builtin_amdgcn_exp2f)
    return __builtin_amdgcn_exp2f(x);
#else
    return exp2f(x);
#endif
}

typedef __attribute__((address_space(1))) const void* as1_cvp;
typedef __attribute__((address_space(3))) void* as3_vp;
__device__ __forceinline__ void cp16(const void* g, void* l) {
    __builtin_amdgcn_global_load_lds((as1_cvp)g, (as3_vp)l, 16, 0, 0);
}
// LDS XOR swizzle (R5, verified: SQ_LDS_BANK_CONFLICT -> 0): slot (row,chunk)
// holds global (row, chunk ^ (row&7)); staging lane fetches global chunk
// (tid&7)^((tid>>3)&7).

// ---------------------------------------------------------------------------
// k_prep: flat-partitioned: blocks [0,2048) convert Wqkv|Wout f32->bf16
// (4 elems/thread); blocks [2048,2560) transpose x [b][c][n]->xt [b][n][c].
// Block 0 lanes<64 also compute M2 = QK_PRESCALE*max|qs*ks|.
// ---------------------------------------------------------------------------
__global__ __launch_bounds__(256) void k_prep(
    const float* __restrict__ Wqkv, const float* __restrict__ Wout,
    const float* __restrict__ x,
    const float* __restrict__ qs, const float* __restrict__ ks,
    unsigned short* __restrict__ Wqkvb, unsigned short* __restrict__ Woutb,
    unsigned short* __restrict__ xt, float* __restrict__ M) {
    const int bx = blockIdx.x;
    if (bx < 2048) {
        if (bx == 0 && threadIdx.x < 64) {
            int lane = threadIdx.x;
            float p = fabsf(qs[lane] * ks[lane]);
#pragma unroll
            for (int off = 1; off < 64; off <<= 1) p = fmaxf(p, __shfl_xor(p, off));
            if (lane == 0) *M = QK_PRESCALE * p;
        }
        int i4 = (bx * 256 + threadIdx.x) * 4;
        const float* src; unsigned short* dst; int idx;
        if (i4 < ODIM * CCH) { src = Wqkv; dst = Wqkvb; idx = i4; }
        else { src = Wout; dst = Woutb; idx = i4 - ODIM * CCH; }
        float4 v = *(const float4*)(src + idx);
        ushort4 o;
        o.x = f2bf(v.x); o.y = f2bf(v.y); o.z = f2bf(v.z); o.w = f2bf(v.w);
        *(ushort4*)(dst + idx) = o;
        return;
    }
    // ---- transpose part ----
    __shared__ unsigned short t[64][65];
    const int fx = bx - 2048;                 // 0..511
    const int n0 = (fx & 31) * 64;
    const int c0 = ((fx >> 5) & 7) * 64;
    const int b  = fx >> 8;
    const int tr = threadIdx.x >> 6, tc = threadIdx.x & 63;
    const float* xs = x + (size_t)b * CCH * NSEQ;
    unsigned short* xd = xt + (size_t)b * NSEQ * CCH;
#pragma unroll
    for (int r = 0; r < 16; ++r) {
        int c = r * 4 + tr;
        t[c][tc] = f2bf(xs[(size_t)(c0 + c) * NSEQ + n0 + tc]);
    }
    __syncthreads();
#pragma unroll
    for (int r = 0; r < 16; ++r) {
        int n = r * 4 + tr;
        xd[(size_t)(n0 + n) * CCH + c0 + tc] = t[tc][n];
    }
}

// ---------------------------------------------------------------------------
// k_gemm_qkv: fused QKV GEMM + l2-norm/scale + head repack (R7 epilogue:
// per-wave LDS transpose, 128B-row global stores).
//   q (part0): qh[bh][n][d] bf16, pre-scaled by QK_PRESCALE
//   k (part1): kh[bh][n][d] bf16
//   v (part2): vb[bh][d][n] bf16
// ---------------------------------------------------------------------------
__global__ __launch_bounds__(256) void k_gemm_qkv(
    const unsigned short* __restrict__ W, const unsigned short* __restrict__ xt,
    const float* __restrict__ qs, const float* __restrict__ ks,
    unsigned short* __restrict__ qh, unsigned short* __restrict__ kh,
    unsigned short* __restrict__ vb) {
    constexpr int K = CCH, N = NSEQ;
    __shared__ __align__(16) short smem[2 * 128 * 64];
    short* lsA = smem;
    short* lsB = smem + 128 * 64;
    const int tid = threadIdx.x, wave = tid >> 6, lane = tid & 63;
    const int l15 = lane & 15, quad = lane >> 4;
    const int n0 = blockIdx.x * 128, m0 = blockIdx.y * 128, z = blockIdx.z;
    const short* Ab = (const short*)W + (size_t)m0 * K;
    const short* Bb = (const short*)xt + ((size_t)z * N + n0) * K;
    const int wm = wave >> 1, wn = wave & 1;
    const int cswz = (((tid & 7) ^ ((tid >> 3) & 7))) * 8;
    const int sw7 = (l15 & 7);

    float4v acc[4][4];
#pragma unroll
    for (int i = 0; i < 4; ++i)
#pragma unroll
        for (int j = 0; j < 4; ++j) acc[i][j] = (float4v){0.f, 0.f, 0.f, 0.f};

    for (int k0 = 0; k0 < K; k0 += 64) {
#pragma unroll
        for (int it = 0; it < 4; ++it) {
            int row = it * 32 + (tid >> 3);
            cp16(Ab + (size_t)row * K + k0 + cswz, &lsA[it * 2048 + wave * 512]);
            cp16(Bb + (size_t)row * K + k0 + cswz, &lsB[it * 2048 + wave * 512]);
        }
        __syncthreads();
        short8 af[4][2], bfr[4][2];
#pragma unroll
        for (int t = 0; t < 4; ++t)
#pragma unroll
            for (int kk = 0; kk < 2; ++kk) {
                af[t][kk]  = *(const short8*)&lsA[(wm * 64 + t * 16 + l15) * 64 + ((kk * 4 + quad) ^ sw7) * 8];
                bfr[t][kk] = *(const short8*)&lsB[(wn * 64 + t * 16 + l15) * 64 + ((kk * 4 + quad) ^ sw7) * 8];
            }
#pragma unroll
        for (int mt = 0; mt < 4; ++mt)
#pragma unroll
            for (int nt = 0; nt < 4; ++nt) {
                acc[mt][nt] = __builtin_amdgcn_mfma_f32_16x16x32_bf16(af[mt][0], bfr[nt][0], acc[mt][nt], 0, 0, 0);
                acc[mt][nt] = __builtin_amdgcn_mfma_f32_16x16x32_bf16(af[mt][1], bfr[nt][1], acc[mt][nt], 0, 0, 0);
            }
        __syncthreads();
    }

    // ---- fused epilogue (per-wave 8KB LDS scratch; intra-wave, no barrier) --
    const int co   = (m0 + wm * 64) >> 6;
    const int part = co >> 4;               // 0=q, 1=k, 2=v
    const int h    = co & 15;
    const int bh   = z * HEADS + h;
    short* myT = smem + wave * 4096;

    if (part < 2) {
        float inv[4];
#pragma unroll
        for (int nt = 0; nt < 4; ++nt) {
            float ss = 0.f;
#pragma unroll
            for (int mt = 0; mt < 4; ++mt)
#pragma unroll
                for (int r = 0; r < 4; ++r) ss += acc[mt][nt][r] * acc[mt][nt][r];
            ss += __shfl_xor(ss, 16);
            ss += __shfl_xor(ss, 32);
            inv[nt] = 1.0f / fmaxf(sqrtf(ss), 1e-12f);
        }
        const float* sc = part ? ks : qs;
        const float csc = part ? 1.0f : QK_PRESCALE;
#pragma unroll
        for (int mt = 0; mt < 4; ++mt) {
            const int db = mt * 16 + quad * 4;
            float4 s4 = *(const float4*)(sc + db);
            s4.x *= csc; s4.y *= csc; s4.z *= csc; s4.w *= csc;
#pragma unroll
            for (int nt = 0; nt < 4; ++nt) {
                int nl = nt * 16 + l15;
                short4v o;
                o.x = (short)f2bf(acc[mt][nt][0] * inv[nt] * s4.x);
                o.y = (short)f2bf(acc[mt][nt][1] * inv[nt] * s4.y);
                o.z = (short)f2bf(acc[mt][nt][2] * inv[nt] * s4.z);
                o.w = (short)f2bf(acc[mt][nt][3] * inv[nt] * s4.w);
                *(short4v*)&myT[nl * 64 + (((db >> 3) ^ (nl & 7)) << 3) + (db & 7)] = o;
            }
        }
        unsigned short* dst = (part ? kh : qh) + (size_t)bh * NSEQ * DHEAD
                              + (size_t)(n0 + wn * 64) * DHEAD;
#pragma unroll
        for (int pass = 0; pass < 8; ++pass) {
            int nl = pass * 8 + (lane >> 3), c = lane & 7;
            short8 vv = *(const short8*)&myT[nl * 64 + ((c ^ (nl & 7)) << 3)];
            *(short8*)&dst[(size_t)nl * DHEAD + c * 8] = vv;
        }
    } else {
#pragma unroll
        for (int mt = 0; mt < 4; ++mt)
#pragma unroll
            for (int nt = 0; nt < 4; ++nt) {
                int nl = nt * 16 + l15;
                int swc = nl >> 3, swo = nl & 7;
#pragma unroll
                for (int r = 0; r < 4; ++r) {
                    int d = mt * 16 + quad * 4 + r;
                    myT[d * 64 + ((swc ^ (d & 7)) << 3) + swo] = (short)f2bf(acc[mt][nt][r]);
                }
            }
        unsigned short* dst = vb + (size_t)bh * DHEAD * NSEQ + n0 + wn * 64;
#pragma unroll
        for (int pass = 0; pass < 8; ++pass) {
            int d = pass * 8 + (lane >> 3), c = lane & 7;
            short8 vv = *(const short8*)&myT[d * 64 + ((c ^ (d & 7)) << 3)];
            *(short8*)&dst[(size_t)d * NSEQ + c * 8] = vv;
        }
    }
}

// ---------------------------------------------------------------------------
// k_attn v3: i-tile 128 (4 waves x 32 rows), full j-loop, dbuf K/V, ONE
// barrier per j-tile (Pt strictly intra-wave), direct normalized aot write.
// Rationale (R8 post-mortem): kernel is LDS-BW-bound; 32 rows/wave amortizes
// the K/V fragment reads over 2x the output rows (per-row LDS bytes x0.58).
// ---------------------------------------------------------------------------
__global__ __launch_bounds__(256, 2) void k_attn(
    const unsigned short* __restrict__ qh, const unsigned short* __restrict__ kh,
    const unsigned short* __restrict__ vb,
    unsigned short* __restrict__ aot, const float* __restrict__ Mptr) {
    __shared__ __align__(16) short Kt[2][64 * 64];
    __shared__ __align__(16) short Vt[2][64 * 64];
    __shared__ __align__(16) short Pt[128 * 64];
    const int tid = threadIdx.x, wave = tid >> 6, lane = tid & 63;
    const int l15 = lane & 15, quad = lane >> 4, q8 = quad * 8;
    // XCD-local decode: 512 blocks = 8 xcd x (4 bh x 16 i-blocks)
    const int flat = blockIdx.x;
    const int xcd = flat & 7, idx = flat >> 3;
    const int bh = xcd * 4 + (idx >> 4);
    const int i0 = (idx & 15) * 128;
    const int b = bh >> 4, h = bh & 15;
    const float Ms = *Mptr;
    const float4v mInit = (float4v){-Ms, -Ms, -Ms, -Ms};
    const int cswz = (((tid & 7) ^ ((tid >> 3) & 7))) * 8;
    const int sw7 = (l15 & 7);
    const int srow = tid >> 3;

    // Q fragments: wave owns rows [i0+wave*32, +32)
    short8 qf[2][2];
    {
        const short* qb = (const short*)qh + ((size_t)bh * NSEQ + i0 + wave * 32) * DHEAD;
#pragma unroll
        for (int mt = 0; mt < 2; ++mt) {
            qf[mt][0] = *(const short8*)&qb[(mt * 16 + l15) * DHEAD + q8];
            qf[mt][1] = *(const short8*)&qb[(mt * 16 + l15) * DHEAD + 32 + q8];
        }
    }

    float4v of[2][4];
#pragma unroll
    for (int mt = 0; mt < 2; ++mt)
#pragma unroll
        for (int dt = 0; dt < 4; ++dt) of[mt][dt] = (float4v){0.f, 0.f, 0.f, 0.f};
    float l_acc[2][4];
#pragma unroll
    for (int mt = 0; mt < 2; ++mt)
#pragma unroll
        for (int r = 0; r < 4; ++r) l_acc[mt][r] = 0.f;

    const short* kbase = (const short*)kh + (size_t)bh * NSEQ * DHEAD;
    const short* vbase = (const short*)vb + (size_t)bh * DHEAD * NSEQ;

    // prologue: stage tile j=0 into buf 0
#pragma unroll
    for (int it = 0; it < 2; ++it) {
        int row = it * 32 + srow;
        cp16(kbase + (size_t)row * DHEAD + cswz, &Kt[0][it * 2048 + wave * 512]);
        cp16(vbase + (size_t)row * NSEQ + cswz, &Vt[0][it * 2048 + wave * 512]);
    }
    __syncthreads();

    int buf = 0;
    for (int j0 = 0; j0 < NSEQ; j0 += 64) {
        if (j0 + 64 < NSEQ) {
            int nb = buf ^ 1;
#pragma unroll
            for (int it = 0; it < 2; ++it) {
                int row = it * 32 + srow;
                cp16(kbase + (size_t)(j0 + 64 + row) * DHEAD + cswz, &Kt[nb][it * 2048 + wave * 512]);
                cp16(vbase + (size_t)row * NSEQ + j0 + 64 + cswz, &Vt[nb][it * 2048 + wave * 512]);
            }
        }

        // S = Q K^T (C-init = -M2); kf shared across both mt sub-tiles
        float4v s[2][4];
#pragma unroll
        for (int nt = 0; nt < 4; ++nt) {
            short8 kf0 = *(const short8*)&Kt[buf][(nt * 16 + l15) * 64 + ((0 + quad) ^ sw7) * 8];
            short8 kf1 = *(const short8*)&Kt[buf][(nt * 16 + l15) * 64 + ((4 + quad) ^ sw7) * 8];
#pragma unroll
            for (int mt = 0; mt < 2; ++mt) {
                float4v zz = mInit;
                zz = __builtin_amdgcn_mfma_f32_16x16x32_bf16(qf[mt][0], kf0, zz, 0, 0, 0);
                zz = __builtin_amdgcn_mfma_f32_16x16x32_bf16(qf[mt][1], kf1, zz, 0, 0, 0);
                s[mt][nt] = zz;
            }
        }

        // softmax: p = exp2(s); Pt stores (intra-wave rows only)
#pragma unroll
        for (int mt = 0; mt < 2; ++mt)
#pragma unroll
            for (int r = 0; r < 4; ++r) {
                int prow = wave * 32 + mt * 16 + quad * 4 + r;
                int psw = prow & 7;
                float p0 = fexp2(s[mt][0][r]);
                float p1 = fexp2(s[mt][1][r]);
                float p2 = fexp2(s[mt][2][r]);
                float p3 = fexp2(s[mt][3][r]);
                l_acc[mt][r] += (p0 + p1) + (p2 + p3);
                Pt[prow * 64 + (((0 + (l15 >> 3)) ^ psw) * 8) + (l15 & 7)] = (short)f2bf_fast(p0);
                Pt[prow * 64 + (((2 + (l15 >> 3)) ^ psw) * 8) + (l15 & 7)] = (short)f2bf_fast(p1);
                Pt[prow * 64 + (((4 + (l15 >> 3)) ^ psw) * 8) + (l15 & 7)] = (short)f2bf_fast(p2);
                Pt[prow * 64 + (((6 + (l15 >> 3)) ^ psw) * 8) + (l15 & 7)] = (short)f2bf_fast(p3);
            }
        // NO barrier: Pt producer == consumer wave (lgkmcnt ordering)

        // O += P V ; vf shared across both mt sub-tiles
        short8 af0[2], af1[2];
#pragma unroll
        for (int mt = 0; mt < 2; ++mt) {
            int arow = wave * 32 + mt * 16 + l15;
            af0[mt] = *(const short8*)&Pt[arow * 64 + ((0 + quad) ^ sw7) * 8];
            af1[mt] = *(const short8*)&Pt[arow * 64 + ((4 + quad) ^ sw7) * 8];
        }
#pragma unroll
        for (int dt = 0; dt < 4; ++dt) {
            short8 vf0 = *(const short8*)&Vt[buf][(dt * 16 + l15) * 64 + ((0 + quad) ^ sw7) * 8];
            short8 vf1 = *(const short8*)&Vt[buf][(dt * 16 + l15) * 64 + ((4 + quad) ^ sw7) * 8];
#pragma unroll
            for (int mt = 0; mt < 2; ++mt) {
                of[mt][dt] = __builtin_amdgcn_mfma_f32_16x16x32_bf16(af0[mt], vf0, of[mt][dt], 0, 0, 0);
                of[mt][dt] = __builtin_amdgcn_mfma_f32_16x16x32_bf16(af1[mt], vf1, of[mt][dt], 0, 0, 0);
            }
        }

        __syncthreads();   // next buf staged + this buf/Pt consumed
        buf ^= 1;
    }

    // l: reduce over the 16 lanes sharing each row; then write normalized aot
#pragma unroll
    for (int mt = 0; mt < 2; ++mt)
#pragma unroll
        for (int r = 0; r < 4; ++r) {
            float l = l_acc[mt][r];
            l += __shfl_xor(l, 1); l += __shfl_xor(l, 2);
            l += __shfl_xor(l, 4); l += __shfl_xor(l, 8);
            l_acc[mt][r] = 1.0f / fmaxf(l, 1e-30f);
        }

#pragma unroll
    for (int mt = 0; mt < 2; ++mt) {
        unsigned short* ob = aot + ((size_t)b * NSEQ + i0 + wave * 32 + mt * 16) * HDIM + h * DHEAD;
#pragma unroll
        for (int dt = 0; dt < 4; ++dt)
#pragma unroll
            for (int r = 0; r < 4; ++r)
                ob[(size_t)(quad * 4 + r) * HDIM + dt * 16 + l15] = f2bf(of[mt][dt][r] * l_acc[mt][r]);
    }
}

// ---------------------------------------------------------------------------
// k_gemm_out: y[b][o][n] f32 = sum_c Wout[o][c]*aot[b][n][c] + bout[o]
// ---------------------------------------------------------------------------
__global__ __launch_bounds__(256) void k_gemm_out(
    const unsigned short* __restrict__ W, const unsigned short* __restrict__ aot,
    const float* __restrict__ bias, float* __restrict__ out) {
    constexpr int K = HDIM, N = NSEQ, M = CCH;
    __shared__ __align__(16) short lsA[64 * 64];
    __shared__ __align__(16) short lsB[64 * 64];
    const int tid = threadIdx.x, wave = tid >> 6, lane = tid & 63;
    const int l15 = lane & 15, quad = lane >> 4;
    const int n0 = blockIdx.x * 64, m0 = blockIdx.y * 64, z = blockIdx.z;
    const short* Ab = (const short*)W + (size_t)m0 * K;
    const short* Bb = (const short*)aot + ((size_t)z * N + n0) * K;
    const int wm = wave >> 1, wn = wave & 1;
    const int cswz = (((tid & 7) ^ ((tid >> 3) & 7))) * 8;
    const int sw7 = (l15 & 7);

    float4v acc[2][2];
#pragma unroll
    for (int i = 0; i < 2; ++i)
#pragma unroll
        for (int j = 0; j < 2; ++j) acc[i][j] = (float4v){0.f, 0.f, 0.f, 0.f};

    for (int k0 = 0; k0 < K; k0 += 64) {
        {
            int row = tid >> 3;
            cp16(Ab + (size_t)row * K + k0 + cswz, &lsA[wave * 512]);
            cp16(Ab + (size_t)(row + 32) * K + k0 + cswz, &lsA[2048 + wave * 512]);
            cp16(Bb + (size_t)row * K + k0 + cswz, &lsB[wave * 512]);
            cp16(Bb + (size_t)(row + 32) * K + k0 + cswz, &lsB[2048 + wave * 512]);
        }
        __syncthreads();
        short8 af[2][2], bfr[2][2];
#pragma unroll
        for (int t = 0; t < 2; ++t)
#pragma unroll
            for (int kk = 0; kk < 2; ++kk) {
                af[t][kk]  = *(const short8*)&lsA[(wm * 32 + t * 16 + l15) * 64 + ((kk * 4 + quad) ^ sw7) * 8];
                bfr[t][kk] = *(const short8*)&lsB[(wn * 32 + t * 16 + l15) * 64 + ((kk * 4 + quad) ^ sw7) * 8];
            }
#pragma unroll
        for (int mt = 0; mt < 2; ++mt)
#pragma unroll
            for (int nt = 0; nt < 2; ++nt) {
                acc[mt][nt] = __builtin_amdgcn_mfma_f32_16x16x32_bf16(af[mt][0], bfr[nt][0], acc[mt][nt], 0, 0, 0);
                acc[mt][nt] = __builtin_amdgcn_mfma_f32_16x16x32_bf16(af[mt][1], bfr[nt][1], acc[mt][nt], 0, 0, 0);
            }
        __syncthreads();
    }
    float* Co = out + (size_t)z * M * N;
#pragma unroll
    for (int mt = 0; mt < 2; ++mt)
#pragma unroll
        for (int nt = 0; nt < 2; ++nt) {
            int mrow = m0 + wm * 32 + mt * 16 + quad * 4;
#pragma unroll
            for (int r = 0; r < 4; ++r) {
                int mr = mrow + r;
                int nc = n0 + wn * 32 + nt * 16 + l15;
                Co[(size_t)mr * N + nc] = acc[mt][nt][r] + bias[mr];
            }
        }
}

// ---------------------------------------------------------------------------
// Launch.  Inputs resolved by element count (f32).
// ---------------------------------------------------------------------------
extern "C" void kernel_launch(void* const* d_in, const int* in_sizes, int n_in,
                              void* d_out, int out_size, void* d_ws, size_t ws_size,
                              hipStream_t stream) {
    const float* x = nullptr; const float* Wqkv = nullptr;
    const float* qs = nullptr; const float* ks = nullptr;
    const float* Wout = nullptr; const float* bout = nullptr;
    for (int i = 0; i < n_in; ++i) {
        switch (in_sizes[i]) {
            case BATCH * CCH * NSEQ: x    = (const float*)d_in[i]; break;
            case ODIM * CCH:         Wqkv = (const float*)d_in[i]; break;
            case CCH * HDIM:         Wout = (const float*)d_in[i]; break;
            case CCH:                bout = (const float*)d_in[i]; break;
            case DHEAD: if (!qs) qs = (const float*)d_in[i]; else ks = (const float*)d_in[i]; break;
            default: break;
        }
    }
    float* y = (float*)d_out;

    char* ws = (char*)d_ws;
    float*          Mbuf  = (float*)(ws + 0);
    unsigned short* Wqkvb = (unsigned short*)(ws + 4096);        // 3,145,728 B
    unsigned short* Woutb = (unsigned short*)(ws + 3149824);     // 1,048,576 B
    unsigned short* xt    = (unsigned short*)(ws + 4198400);     // 4,194,304 B
    unsigned short* qh    = (unsigned short*)(ws + 8392704);     // 8,388,608 B
    unsigned short* kh    = (unsigned short*)(ws + 16781312);    // 8,388,608 B
    unsigned short* vb    = (unsigned short*)(ws + 25169920);    // 8,388,608 B
    unsigned short* aot   = (unsigned short*)(ws + 33558528);    // 8,388,608 B -> 41,947,136

    k_prep<<<dim3(2048 + 512), 256, 0, stream>>>(Wqkv, Wout, x, qs, ks, Wqkvb, Woutb, xt, Mbuf);
    k_gemm_qkv<<<dim3(NSEQ / 128, ODIM / 128, BATCH), 256, 0, stream>>>(Wqkvb, xt, qs, ks, qh, kh, vb);
    k_attn<<<dim3(512), 256, 0, stream>>>(qh, kh, vb, aot, Mbuf);
    k_gemm_out<<<dim3(NSEQ / 64, CCH / 64, BATCH), 256, 0, stream>>>(Woutb, aot, bout, y);
}

// Round 11
// 153.913 us; speedup vs baseline: 1.1486x; 1.0484x over previous
//
#include <hip/hip_runtime.h>
#include <hip/hip_bf16.h>

// ---------------------------------------------------------------------------
// Problem constants.  Inputs f32, output f32 (proven R4).
// ---------------------------------------------------------------------------
#define BATCH 2
#define CCH   512
#define NSEQ  2048
#define HEADS 16
#define DHEAD 64
#define HDIM  1024
#define ODIM  3072
// 8 * log2(e): folded into q-hat at the GEMM epilogue; M2 = this * max|qs*ks|.
#define QK_PRESCALE 11.541560327111707f

typedef short short4v __attribute__((ext_vector_type(4)));
typedef short short8 __attribute__((ext_vector_type(8)));
typedef float float4v __attribute__((ext_vector_type(4)));

__device__ __forceinline__ unsigned short f2bf(float f) {          // RNE
    unsigned int u = __float_as_uint(f);
    return (unsigned short)((u + 0x7FFFu + ((u >> 16) & 1u)) >> 16);
}
__device__ __forceinline__ unsigned short f2bf_fast(float f) {     // round-half-up
    return (unsigned short)((__float_as_uint(f) + 0x8000u) >> 16);
}
__device__ __forceinline__ float fexp2(float x) {
#if __has_builtin(__builtin_amdgcn_exp2f)
    return __builtin_amdgcn_exp2f(x);
#else
    return exp2f(x);
#endif
}

typedef __attribute__((address_space(1))) const void* as1_cvp;
typedef __attribute__((address_space(3))) void* as3_vp;
__device__ __forceinline__ void cp16(const void* g, void* l) {
    __builtin_amdgcn_global_load_lds((as1_cvp)g, (as3_vp)l, 16, 0, 0);
}
// LDS XOR swizzle (R5, verified: SQ_LDS_BANK_CONFLICT -> 0): slot (row,chunk)
// holds global (row, chunk ^ (row&7)); staging lane fetches global chunk
// (tid&7)^((tid>>3)&7).

// ---------------------------------------------------------------------------
// k_prep: blocks [0,2048) convert Wqkv|Wout f32->bf16; blocks [2048,2560)
// transpose x [b][c][n] -> xt [b][n][c].  Block 0 also computes M2.
// ---------------------------------------------------------------------------
__global__ __launch_bounds__(256) void k_prep(
    const float* __restrict__ Wqkv, const float* __restrict__ Wout,
    const float* __restrict__ x,
    const float* __restrict__ qs, const float* __restrict__ ks,
    unsigned short* __restrict__ Wqkvb, unsigned short* __restrict__ Woutb,
    unsigned short* __restrict__ xt, float* __restrict__ M) {
    const int bx = blockIdx.x;
    if (bx < 2048) {
        if (bx == 0 && threadIdx.x < 64) {
            int lane = threadIdx.x;
            float p = fabsf(qs[lane] * ks[lane]);
#pragma unroll
            for (int off = 1; off < 64; off <<= 1) p = fmaxf(p, __shfl_xor(p, off));
            if (lane == 0) *M = QK_PRESCALE * p;
        }
        int i4 = (bx * 256 + threadIdx.x) * 4;
        const float* src; unsigned short* dst; int idx;
        if (i4 < ODIM * CCH) { src = Wqkv; dst = Wqkvb; idx = i4; }
        else { src = Wout; dst = Woutb; idx = i4 - ODIM * CCH; }
        float4 v = *(const float4*)(src + idx);
        ushort4 o;
        o.x = f2bf(v.x); o.y = f2bf(v.y); o.z = f2bf(v.z); o.w = f2bf(v.w);
        *(ushort4*)(dst + idx) = o;
        return;
    }
    __shared__ unsigned short t[64][65];
    const int fx = bx - 2048;
    const int n0 = (fx & 31) * 64;
    const int c0 = ((fx >> 5) & 7) * 64;
    const int b  = fx >> 8;
    const int tr = threadIdx.x >> 6, tc = threadIdx.x & 63;
    const float* xs = x + (size_t)b * CCH * NSEQ;
    unsigned short* xd = xt + (size_t)b * NSEQ * CCH;
#pragma unroll
    for (int r = 0; r < 16; ++r) {
        int c = r * 4 + tr;
        t[c][tc] = f2bf(xs[(size_t)(c0 + c) * NSEQ + n0 + tc]);
    }
    __syncthreads();
#pragma unroll
    for (int r = 0; r < 16; ++r) {
        int n = r * 4 + tr;
        xd[(size_t)(n0 + n) * CCH + c0 + tc] = t[tc][n];
    }
}

// ---------------------------------------------------------------------------
// k_gemm_qkv: fused QKV GEMM + l2-norm/scale + head repack (R7 epilogue:
// per-wave LDS transpose, 128B-row global stores).  Unchanged from R9.
// ---------------------------------------------------------------------------
__global__ __launch_bounds__(256) void k_gemm_qkv(
    const unsigned short* __restrict__ W, const unsigned short* __restrict__ xt,
    const float* __restrict__ qs, const float* __restrict__ ks,
    unsigned short* __restrict__ qh, unsigned short* __restrict__ kh,
    unsigned short* __restrict__ vb) {
    constexpr int K = CCH, N = NSEQ;
    __shared__ __align__(16) short smem[2 * 128 * 64];
    short* lsA = smem;
    short* lsB = smem + 128 * 64;
    const int tid = threadIdx.x, wave = tid >> 6, lane = tid & 63;
    const int l15 = lane & 15, quad = lane >> 4;
    const int n0 = blockIdx.x * 128, m0 = blockIdx.y * 128, z = blockIdx.z;
    const short* Ab = (const short*)W + (size_t)m0 * K;
    const short* Bb = (const short*)xt + ((size_t)z * N + n0) * K;
    const int wm = wave >> 1, wn = wave & 1;
    const int cswz = (((tid & 7) ^ ((tid >> 3) & 7))) * 8;
    const int sw7 = (l15 & 7);

    float4v acc[4][4];
#pragma unroll
    for (int i = 0; i < 4; ++i)
#pragma unroll
        for (int j = 0; j < 4; ++j) acc[i][j] = (float4v){0.f, 0.f, 0.f, 0.f};

    for (int k0 = 0; k0 < K; k0 += 64) {
#pragma unroll
        for (int it = 0; it < 4; ++it) {
            int row = it * 32 + (tid >> 3);
            cp16(Ab + (size_t)row * K + k0 + cswz, &lsA[it * 2048 + wave * 512]);
            cp16(Bb + (size_t)row * K + k0 + cswz, &lsB[it * 2048 + wave * 512]);
        }
        __syncthreads();
        short8 af[4][2], bfr[4][2];
#pragma unroll
        for (int t = 0; t < 4; ++t)
#pragma unroll
            for (int kk = 0; kk < 2; ++kk) {
                af[t][kk]  = *(const short8*)&lsA[(wm * 64 + t * 16 + l15) * 64 + ((kk * 4 + quad) ^ sw7) * 8];
                bfr[t][kk] = *(const short8*)&lsB[(wn * 64 + t * 16 + l15) * 64 + ((kk * 4 + quad) ^ sw7) * 8];
            }
#pragma unroll
        for (int mt = 0; mt < 4; ++mt)
#pragma unroll
            for (int nt = 0; nt < 4; ++nt) {
                acc[mt][nt] = __builtin_amdgcn_mfma_f32_16x16x32_bf16(af[mt][0], bfr[nt][0], acc[mt][nt], 0, 0, 0);
                acc[mt][nt] = __builtin_amdgcn_mfma_f32_16x16x32_bf16(af[mt][1], bfr[nt][1], acc[mt][nt], 0, 0, 0);
            }
        __syncthreads();
    }

    const int co   = (m0 + wm * 64) >> 6;
    const int part = co >> 4;               // 0=q, 1=k, 2=v
    const int h    = co & 15;
    const int bh   = z * HEADS + h;
    short* myT = smem + wave * 4096;

    if (part < 2) {
        float inv[4];
#pragma unroll
        for (int nt = 0; nt < 4; ++nt) {
            float ss = 0.f;
#pragma unroll
            for (int mt = 0; mt < 4; ++mt)
#pragma unroll
                for (int r = 0; r < 4; ++r) ss += acc[mt][nt][r] * acc[mt][nt][r];
            ss += __shfl_xor(ss, 16);
            ss += __shfl_xor(ss, 32);
            inv[nt] = 1.0f / fmaxf(sqrtf(ss), 1e-12f);
        }
        const float* sc = part ? ks : qs;
        const float csc = part ? 1.0f : QK_PRESCALE;
#pragma unroll
        for (int mt = 0; mt < 4; ++mt) {
            const int db = mt * 16 + quad * 4;
            float4 s4 = *(const float4*)(sc + db);
            s4.x *= csc; s4.y *= csc; s4.z *= csc; s4.w *= csc;
#pragma unroll
            for (int nt = 0; nt < 4; ++nt) {
                int nl = nt * 16 + l15;
                short4v o;
                o.x = (short)f2bf(acc[mt][nt][0] * inv[nt] * s4.x);
                o.y = (short)f2bf(acc[mt][nt][1] * inv[nt] * s4.y);
                o.z = (short)f2bf(acc[mt][nt][2] * inv[nt] * s4.z);
                o.w = (short)f2bf(acc[mt][nt][3] * inv[nt] * s4.w);
                *(short4v*)&myT[nl * 64 + (((db >> 3) ^ (nl & 7)) << 3) + (db & 7)] = o;
            }
        }
        unsigned short* dst = (part ? kh : qh) + (size_t)bh * NSEQ * DHEAD
                              + (size_t)(n0 + wn * 64) * DHEAD;
#pragma unroll
        for (int pass = 0; pass < 8; ++pass) {
            int nl = pass * 8 + (lane >> 3), c = lane & 7;
            short8 vv = *(const short8*)&myT[nl * 64 + ((c ^ (nl & 7)) << 3)];
            *(short8*)&dst[(size_t)nl * DHEAD + c * 8] = vv;
        }
    } else {
#pragma unroll
        for (int mt = 0; mt < 4; ++mt)
#pragma unroll
            for (int nt = 0; nt < 4; ++nt) {
                int nl = nt * 16 + l15;
                int swc = nl >> 3, swo = nl & 7;
#pragma unroll
                for (int r = 0; r < 4; ++r) {
                    int d = mt * 16 + quad * 4 + r;
                    myT[d * 64 + ((swc ^ (d & 7)) << 3) + swo] = (short)f2bf(acc[mt][nt][r]);
                }
            }
        unsigned short* dst = vb + (size_t)bh * DHEAD * NSEQ + n0 + wn * 64;
#pragma unroll
        for (int pass = 0; pass < 8; ++pass) {
            int d = pass * 8 + (lane >> 3), c = lane & 7;
            short8 vv = *(const short8*)&myT[d * 64 + ((c ^ (d & 7)) << 3)];
            *(short8*)&dst[(size_t)d * NSEQ + c * 8] = vv;
        }
    }
}

// ---------------------------------------------------------------------------
// k_attn v5: transpose-free P using ONLY mfma_f32_16x16x32_bf16.
// S^T = K·Q^T computed in two 16-row tiles whose A-rows are the PERMUTED
// K rows f_t(m) = (m>>2)*8 + t*4 + (m&3)  (t=0,1).  Then tile t's C output
// at lane (quad,l15) reg r is S^T[j = quad*8 + t*4 + r][i = l15] — exactly
// element t*4+r of the K=32 PV B-operand (B[n=lane&15][k=quad*8+idx]).
// P never touches LDS.  PV A-operand = V^T short8 rows from Vt [d][j].
// Per wave-tile LDS = K 8KB + V 8KB (minimum).  i-tile 128, dbuf, 1 barrier.
// ---------------------------------------------------------------------------
__global__ __launch_bounds__(256, 2) void k_attn(
    const unsigned short* __restrict__ qh, const unsigned short* __restrict__ kh,
    const unsigned short* __restrict__ vb,
    unsigned short* __restrict__ aot, const float* __restrict__ Mptr) {
    __shared__ __align__(16) short Kt[2][64 * 64];
    __shared__ __align__(16) short Vt[2][64 * 64];
    const int tid = threadIdx.x, wave = tid >> 6, lane = tid & 63;
    const int l15 = lane & 15, quad = lane >> 4, q8 = quad * 8;
    const int flat = blockIdx.x;
    const int xcd = flat & 7, idx = flat >> 3;
    const int bh = xcd * 4 + (idx >> 4);
    const int i0 = (idx & 15) * 128;
    const int b = bh >> 4, h = bh & 15;
    const float Ms = *Mptr;
    const float4v mInit = (float4v){-Ms, -Ms, -Ms, -Ms};
    const int cswz = (((tid & 7) ^ ((tid >> 3) & 7))) * 8;
    const int srow = tid >> 3;
    // permuted A-row indices (within a 32-j chunk) for the two S^T tiles
    const int ar0 = (l15 >> 2) * 8 + (l15 & 3);   // t=0
    const int ar1 = ar0 + 4;                      // t=1

    // Q fragments (B-operand of S^T): rows it*16+l15, d-slices quad*8
    short8 qf[2][2];
    {
        const short* qb = (const short*)qh + ((size_t)bh * NSEQ + i0 + wave * 32) * DHEAD;
#pragma unroll
        for (int it = 0; it < 2; ++it) {
            qf[it][0] = *(const short8*)&qb[(it * 16 + l15) * DHEAD + q8];
            qf[it][1] = *(const short8*)&qb[(it * 16 + l15) * DHEAD + 32 + q8];
        }
    }

    float4v of[2][4];
#pragma unroll
    for (int it = 0; it < 2; ++it)
#pragma unroll
        for (int dt = 0; dt < 4; ++dt) of[it][dt] = (float4v){0.f, 0.f, 0.f, 0.f};
    float l_acc[2] = {0.f, 0.f};

    const short* kbase = (const short*)kh + (size_t)bh * NSEQ * DHEAD;
    const short* vbase = (const short*)vb + (size_t)bh * DHEAD * NSEQ;

#pragma unroll
    for (int it = 0; it < 2; ++it) {
        int row = it * 32 + srow;
        cp16(kbase + (size_t)row * DHEAD + cswz, &Kt[0][it * 2048 + wave * 512]);
        cp16(vbase + (size_t)row * NSEQ + cswz, &Vt[0][it * 2048 + wave * 512]);
    }
    __syncthreads();

    int buf = 0;
    for (int j0 = 0; j0 < NSEQ; j0 += 64) {
        if (j0 + 64 < NSEQ) {
            int nb = buf ^ 1;
#pragma unroll
            for (int it = 0; it < 2; ++it) {
                int row = it * 32 + srow;
                cp16(kbase + (size_t)(j0 + 64 + row) * DHEAD + cswz, &Kt[nb][it * 2048 + wave * 512]);
                cp16(vbase + (size_t)row * NSEQ + j0 + 64 + cswz, &Vt[nb][it * 2048 + wave * 512]);
            }
        }

#pragma unroll
        for (int ch = 0; ch < 2; ++ch) {
            short8 pb[2];
#pragma unroll
            for (int t = 0; t < 2; ++t) {
                const int arow = ch * 32 + (t ? ar1 : ar0);
                const int asw = arow & 7;
                const short* kr = &Kt[buf][arow * 64];
                short8 kf0 = *(const short8*)&kr[((0 + quad) ^ asw) * 8];
                short8 kf1 = *(const short8*)&kr[((4 + quad) ^ asw) * 8];
#pragma unroll
                for (int it = 0; it < 2; ++it) {
                    float4v s = mInit;
                    s = __builtin_amdgcn_mfma_f32_16x16x32_bf16(kf0, qf[it][0], s, 0, 0, 0);
                    s = __builtin_amdgcn_mfma_f32_16x16x32_bf16(kf1, qf[it][1], s, 0, 0, 0);
                    float p0 = fexp2(s[0]);
                    float p1 = fexp2(s[1]);
                    float p2 = fexp2(s[2]);
                    float p3 = fexp2(s[3]);
                    l_acc[it] += (p0 + p1) + (p2 + p3);
                    pb[it][t * 4 + 0] = (short)f2bf_fast(p0);
                    pb[it][t * 4 + 1] = (short)f2bf_fast(p1);
                    pb[it][t * 4 + 2] = (short)f2bf_fast(p2);
                    pb[it][t * 4 + 3] = (short)f2bf_fast(p3);
                }
            }
            // O^T += V^T P^T (A = V^T short8, B = pb register P)
#pragma unroll
            for (int dt = 0; dt < 4; ++dt) {
                int vrow = dt * 16 + l15;
                int vsw = vrow & 7;
                short8 av = *(const short8*)&Vt[buf][vrow * 64 + (((ch * 4 + quad) ^ vsw)) * 8];
                of[0][dt] = __builtin_amdgcn_mfma_f32_16x16x32_bf16(av, pb[0], of[0][dt], 0, 0, 0);
                of[1][dt] = __builtin_amdgcn_mfma_f32_16x16x32_bf16(av, pb[1], of[1][dt], 0, 0, 0);
            }
        }

        __syncthreads();   // next buf staged + this buf consumed
        buf ^= 1;
    }

    // l per i: sum across the 4 quads; write normalized O^T rows
#pragma unroll
    for (int it = 0; it < 2; ++it) {
        float l = l_acc[it];
        l += __shfl_xor(l, 16);
        l += __shfl_xor(l, 32);
        float inv = 1.0f / fmaxf(l, 1e-30f);
        unsigned short* ob = aot + ((size_t)b * NSEQ + i0 + wave * 32 + it * 16 + l15) * HDIM + h * DHEAD;
#pragma unroll
        for (int dt = 0; dt < 4; ++dt) {
            ushort4 o;
            o.x = f2bf(of[it][dt][0] * inv);
            o.y = f2bf(of[it][dt][1] * inv);
            o.z = f2bf(of[it][dt][2] * inv);
            o.w = f2bf(of[it][dt][3] * inv);
            *(ushort4*)&ob[dt * 16 + quad * 4] = o;
        }
    }
}

// ---------------------------------------------------------------------------
// k_gemm_out v2: 128m x 64n tiles (2x FLOP/LDS-byte vs 64x64).
// y[b][o][n] f32 = sum_c Wout[o][c]*aot[b][n][c] + bout[o]
// ---------------------------------------------------------------------------
__global__ __launch_bounds__(256) void k_gemm_out(
    const unsigned short* __restrict__ W, const unsigned short* __restrict__ aot,
    const float* __restrict__ bias, float* __restrict__ out) {
    constexpr int K = HDIM, N = NSEQ, M = CCH;
    __shared__ __align__(16) short lsA[128 * 64];
    __shared__ __align__(16) short lsB[64 * 64];
    const int tid = threadIdx.x, wave = tid >> 6, lane = tid & 63;
    const int l15 = lane & 15, quad = lane >> 4;
    const int n0 = blockIdx.x * 64, m0 = blockIdx.y * 128, z = blockIdx.z;
    const short* Ab = (const short*)W + (size_t)m0 * K;
    const short* Bb = (const short*)aot + ((size_t)z * N + n0) * K;
    const int wm = wave >> 1, wn = wave & 1;
    const int cswz = (((tid & 7) ^ ((tid >> 3) & 7))) * 8;
    const int sw7 = (l15 & 7);
    const int srow = tid >> 3;

    float4v acc[4][2];
#pragma unroll
    for (int i = 0; i < 4; ++i)
#pragma unroll
        for (int j = 0; j < 2; ++j) acc[i][j] = (float4v){0.f, 0.f, 0.f, 0.f};

    for (int k0 = 0; k0 < K; k0 += 64) {
#pragma unroll
        for (int it = 0; it < 4; ++it) {
            int row = it * 32 + srow;
            cp16(Ab + (size_t)row * K + k0 + cswz, &lsA[it * 2048 + wave * 512]);
        }
#pragma unroll
        for (int it = 0; it < 2; ++it) {
            int row = it * 32 + srow;
            cp16(Bb + (size_t)row * K + k0 + cswz, &lsB[it * 2048 + wave * 512]);
        }
        __syncthreads();
        short8 af[4][2], bfr[2][2];
#pragma unroll
        for (int t = 0; t < 4; ++t)
#pragma unroll
            for (int kk = 0; kk < 2; ++kk)
                af[t][kk] = *(const short8*)&lsA[(wm * 64 + t * 16 + l15) * 64 + ((kk * 4 + quad) ^ sw7) * 8];
#pragma unroll
        for (int t = 0; t < 2; ++t)
#pragma unroll
            for (int kk = 0; kk < 2; ++kk)
                bfr[t][kk] = *(const short8*)&lsB[(wn * 32 + t * 16 + l15) * 64 + ((kk * 4 + quad) ^ sw7) * 8];
#pragma unroll
        for (int mt = 0; mt < 4; ++mt)
#pragma unroll
            for (int nt = 0; nt < 2; ++nt) {
                acc[mt][nt] = __builtin_amdgcn_mfma_f32_16x16x32_bf16(af[mt][0], bfr[nt][0], acc[mt][nt], 0, 0, 0);
                acc[mt][nt] = __builtin_amdgcn_mfma_f32_16x16x32_bf16(af[mt][1], bfr[nt][1], acc[mt][nt], 0, 0, 0);
            }
        __syncthreads();
    }
    float* Co = out + (size_t)z * M * N;
#pragma unroll
    for (int mt = 0; mt < 4; ++mt)
#pragma unroll
        for (int nt = 0; nt < 2; ++nt) {
            int mrow = m0 + wm * 64 + mt * 16 + quad * 4;
#pragma unroll
            for (int r = 0; r < 4; ++r) {
                int mr = mrow + r;
                int nc = n0 + wn * 32 + nt * 16 + l15;
                Co[(size_t)mr * N + nc] = acc[mt][nt][r] + bias[mr];
            }
        }
}

// ---------------------------------------------------------------------------
// Launch.  Inputs resolved by element count (f32).
// ---------------------------------------------------------------------------
extern "C" void kernel_launch(void* const* d_in, const int* in_sizes, int n_in,
                              void* d_out, int out_size, void* d_ws, size_t ws_size,
                              hipStream_t stream) {
    const float* x = nullptr; const float* Wqkv = nullptr;
    const float* qs = nullptr; const float* ks = nullptr;
    const float* Wout = nullptr; const float* bout = nullptr;
    for (int i = 0; i < n_in; ++i) {
        switch (in_sizes[i]) {
            case BATCH * CCH * NSEQ: x    = (const float*)d_in[i]; break;
            case ODIM * CCH:         Wqkv = (const float*)d_in[i]; break;
            case CCH * HDIM:         Wout = (const float*)d_in[i]; break;
            case CCH:                bout = (const float*)d_in[i]; break;
            case DHEAD: if (!qs) qs = (const float*)d_in[i]; else ks = (const float*)d_in[i]; break;
            default: break;
        }
    }
    float* y = (float*)d_out;

    char* ws = (char*)d_ws;
    float*          Mbuf  = (float*)(ws + 0);
    unsigned short* Wqkvb = (unsigned short*)(ws + 4096);        // 3,145,728 B
    unsigned short* Woutb = (unsigned short*)(ws + 3149824);     // 1,048,576 B
    unsigned short* xt    = (unsigned short*)(ws + 4198400);     // 4,194,304 B
    unsigned short* qh    = (unsigned short*)(ws + 8392704);     // 8,388,608 B
    unsigned short* kh    = (unsigned short*)(ws + 16781312);    // 8,388,608 B
    unsigned short* vb    = (unsigned short*)(ws + 25169920);    // 8,388,608 B
    unsigned short* aot   = (unsigned short*)(ws + 33558528);    // 8,388,608 B -> 41,947,136

    k_prep<<<dim3(2048 + 512), 256, 0, stream>>>(Wqkv, Wout, x, qs, ks, Wqkvb, Woutb, xt, Mbuf);
    k_gemm_qkv<<<dim3(NSEQ / 128, ODIM / 128, BATCH), 256, 0, stream>>>(Wqkvb, xt, qs, ks, qh, kh, vb);
    k_attn<<<dim3(512), 256, 0, stream>>>(qh, kh, vb, aot, Mbuf);
    k_gemm_out<<<dim3(NSEQ / 64, CCH / 128, BATCH), 256, 0, stream>>>(Woutb, aot, bout, y);
}

// Round 12
// 147.273 us; speedup vs baseline: 1.2004x; 1.0451x over previous
//
#include <hip/hip_runtime.h>
#include <hip/hip_bf16.h>

// ---------------------------------------------------------------------------
// Problem constants.  Inputs f32, output f32 (proven R4).
// ---------------------------------------------------------------------------
#define BATCH 2
#define CCH   512
#define NSEQ  2048
#define HEADS 16
#define DHEAD 64
#define HDIM  1024
#define ODIM  3072
// 8 * log2(e): folded into q-hat at the GEMM epilogue; M2 = this * max|qs*ks|.
#define QK_PRESCALE 11.541560327111707f

typedef short short4v __attribute__((ext_vector_type(4)));
typedef short short8 __attribute__((ext_vector_type(8)));
typedef float float4v __attribute__((ext_vector_type(4)));
typedef int   int4v   __attribute__((ext_vector_type(4)));

__device__ __forceinline__ unsigned short f2bf(float f) {          // RNE
    unsigned int u = __float_as_uint(f);
    return (unsigned short)((u + 0x7FFFu + ((u >> 16) & 1u)) >> 16);
}
__device__ __forceinline__ unsigned short f2bf_fast(float f) {     // round-half-up
    return (unsigned short)((__float_as_uint(f) + 0x8000u) >> 16);
}
__device__ __forceinline__ float fexp2(float x) {
#if __has_builtin(__builtin_amdgcn_exp2f)
    return __builtin_amdgcn_exp2f(x);
#else
    return exp2f(x);
#endif
}
// pack two f32 -> one dword of two bf16 (lo, hi)
__device__ __forceinline__ int pack_bf16(float lo, float hi) {
#if __has_builtin(__builtin_amdgcn_cvt_pk_bf16_f32)
    typedef __bf16 bf2_t __attribute__((ext_vector_type(2)));
    bf2_t v = __builtin_amdgcn_cvt_pk_bf16_f32(lo, hi);
    return __builtin_bit_cast(int, v);
#else
    return (int)f2bf_fast(lo) | ((int)(unsigned)f2bf_fast(hi) << 16);
#endif
}

typedef __attribute__((address_space(1))) const void* as1_cvp;
typedef __attribute__((address_space(3))) void* as3_vp;
__device__ __forceinline__ void cp16(const void* g, void* l) {
    __builtin_amdgcn_global_load_lds((as1_cvp)g, (as3_vp)l, 16, 0, 0);
}
// LDS XOR swizzle (R5, verified: SQ_LDS_BANK_CONFLICT -> 0): slot (row,chunk)
// holds global (row, chunk ^ key(row)); staging lane fetches global chunk
// (lane&7)^key(row).  Default key = row&7.  Kt in k_attn uses the finer
// key(row) = (row&3)|(((row>>3)&1)<<2) so the PERMUTED A-row reads (R11's
// 4-way, 2.1M conflicts) become 2-way/free: reader key folds to l15&7.
// ---------------------------------------------------------------------------
// k_prep: blocks [0,2048) convert Wqkv|Wout f32->bf16; blocks [2048,2560)
// transpose x [b][c][n] -> xt [b][n][c].  Block 0 also computes M2.
// ---------------------------------------------------------------------------
__global__ __launch_bounds__(256) void k_prep(
    const float* __restrict__ Wqkv, const float* __restrict__ Wout,
    const float* __restrict__ x,
    const float* __restrict__ qs, const float* __restrict__ ks,
    unsigned short* __restrict__ Wqkvb, unsigned short* __restrict__ Woutb,
    unsigned short* __restrict__ xt, float* __restrict__ M) {
    const int bx = blockIdx.x;
    if (bx < 2048) {
        if (bx == 0 && threadIdx.x < 64) {
            int lane = threadIdx.x;
            float p = fabsf(qs[lane] * ks[lane]);
#pragma unroll
            for (int off = 1; off < 64; off <<= 1) p = fmaxf(p, __shfl_xor(p, off));
            if (lane == 0) *M = QK_PRESCALE * p;
        }
        int i4 = (bx * 256 + threadIdx.x) * 4;
        const float* src; unsigned short* dst; int idx;
        if (i4 < ODIM * CCH) { src = Wqkv; dst = Wqkvb; idx = i4; }
        else { src = Wout; dst = Woutb; idx = i4 - ODIM * CCH; }
        float4 v = *(const float4*)(src + idx);
        ushort4 o;
        o.x = f2bf(v.x); o.y = f2bf(v.y); o.z = f2bf(v.z); o.w = f2bf(v.w);
        *(ushort4*)(dst + idx) = o;
        return;
    }
    __shared__ unsigned short t[64][65];
    const int fx = bx - 2048;
    const int n0 = (fx & 31) * 64;
    const int c0 = ((fx >> 5) & 7) * 64;
    const int b  = fx >> 8;
    const int tr = threadIdx.x >> 6, tc = threadIdx.x & 63;
    const float* xs = x + (size_t)b * CCH * NSEQ;
    unsigned short* xd = xt + (size_t)b * NSEQ * CCH;
#pragma unroll
    for (int r = 0; r < 16; ++r) {
        int c = r * 4 + tr;
        t[c][tc] = f2bf(xs[(size_t)(c0 + c) * NSEQ + n0 + tc]);
    }
    __syncthreads();
#pragma unroll
    for (int r = 0; r < 16; ++r) {
        int n = r * 4 + tr;
        xd[(size_t)(n0 + n) * CCH + c0 + tc] = t[tc][n];
    }
}

// ---------------------------------------------------------------------------
// k_gemm_qkv: fused QKV GEMM + l2-norm/scale + head repack (R7 epilogue:
// per-wave LDS transpose, 128B-row global stores).  Unchanged from R9.
// ---------------------------------------------------------------------------
__global__ __launch_bounds__(256) void k_gemm_qkv(
    const unsigned short* __restrict__ W, const unsigned short* __restrict__ xt,
    const float* __restrict__ qs, const float* __restrict__ ks,
    unsigned short* __restrict__ qh, unsigned short* __restrict__ kh,
    unsigned short* __restrict__ vb) {
    constexpr int K = CCH, N = NSEQ;
    __shared__ __align__(16) short smem[2 * 128 * 64];
    short* lsA = smem;
    short* lsB = smem + 128 * 64;
    const int tid = threadIdx.x, wave = tid >> 6, lane = tid & 63;
    const int l15 = lane & 15, quad = lane >> 4;
    const int n0 = blockIdx.x * 128, m0 = blockIdx.y * 128, z = blockIdx.z;
    const short* Ab = (const short*)W + (size_t)m0 * K;
    const short* Bb = (const short*)xt + ((size_t)z * N + n0) * K;
    const int wm = wave >> 1, wn = wave & 1;
    const int cswz = (((tid & 7) ^ ((tid >> 3) & 7))) * 8;
    const int sw7 = (l15 & 7);

    float4v acc[4][4];
#pragma unroll
    for (int i = 0; i < 4; ++i)
#pragma unroll
        for (int j = 0; j < 4; ++j) acc[i][j] = (float4v){0.f, 0.f, 0.f, 0.f};

    for (int k0 = 0; k0 < K; k0 += 64) {
#pragma unroll
        for (int it = 0; it < 4; ++it) {
            int row = it * 32 + (tid >> 3);
            cp16(Ab + (size_t)row * K + k0 + cswz, &lsA[it * 2048 + wave * 512]);
            cp16(Bb + (size_t)row * K + k0 + cswz, &lsB[it * 2048 + wave * 512]);
        }
        __syncthreads();
        short8 af[4][2], bfr[4][2];
#pragma unroll
        for (int t = 0; t < 4; ++t)
#pragma unroll
            for (int kk = 0; kk < 2; ++kk) {
                af[t][kk]  = *(const short8*)&lsA[(wm * 64 + t * 16 + l15) * 64 + ((kk * 4 + quad) ^ sw7) * 8];
                bfr[t][kk] = *(const short8*)&lsB[(wn * 64 + t * 16 + l15) * 64 + ((kk * 4 + quad) ^ sw7) * 8];
            }
#pragma unroll
        for (int mt = 0; mt < 4; ++mt)
#pragma unroll
            for (int nt = 0; nt < 4; ++nt) {
                acc[mt][nt] = __builtin_amdgcn_mfma_f32_16x16x32_bf16(af[mt][0], bfr[nt][0], acc[mt][nt], 0, 0, 0);
                acc[mt][nt] = __builtin_amdgcn_mfma_f32_16x16x32_bf16(af[mt][1], bfr[nt][1], acc[mt][nt], 0, 0, 0);
            }
        __syncthreads();
    }

    const int co   = (m0 + wm * 64) >> 6;
    const int part = co >> 4;               // 0=q, 1=k, 2=v
    const int h    = co & 15;
    const int bh   = z * HEADS + h;
    short* myT = smem + wave * 4096;

    if (part < 2) {
        float inv[4];
#pragma unroll
        for (int nt = 0; nt < 4; ++nt) {
            float ss = 0.f;
#pragma unroll
            for (int mt = 0; mt < 4; ++mt)
#pragma unroll
                for (int r = 0; r < 4; ++r) ss += acc[mt][nt][r] * acc[mt][nt][r];
            ss += __shfl_xor(ss, 16);
            ss += __shfl_xor(ss, 32);
            inv[nt] = 1.0f / fmaxf(sqrtf(ss), 1e-12f);
        }
        const float* sc = part ? ks : qs;
        const float csc = part ? 1.0f : QK_PRESCALE;
#pragma unroll
        for (int mt = 0; mt < 4; ++mt) {
            const int db = mt * 16 + quad * 4;
            float4 s4 = *(const float4*)(sc + db);
            s4.x *= csc; s4.y *= csc; s4.z *= csc; s4.w *= csc;
#pragma unroll
            for (int nt = 0; nt < 4; ++nt) {
                int nl = nt * 16 + l15;
                short4v o;
                o.x = (short)f2bf(acc[mt][nt][0] * inv[nt] * s4.x);
                o.y = (short)f2bf(acc[mt][nt][1] * inv[nt] * s4.y);
                o.z = (short)f2bf(acc[mt][nt][2] * inv[nt] * s4.z);
                o.w = (short)f2bf(acc[mt][nt][3] * inv[nt] * s4.w);
                *(short4v*)&myT[nl * 64 + (((db >> 3) ^ (nl & 7)) << 3) + (db & 7)] = o;
            }
        }
        unsigned short* dst = (part ? kh : qh) + (size_t)bh * NSEQ * DHEAD
                              + (size_t)(n0 + wn * 64) * DHEAD;
#pragma unroll
        for (int pass = 0; pass < 8; ++pass) {
            int nl = pass * 8 + (lane >> 3), c = lane & 7;
            short8 vv = *(const short8*)&myT[nl * 64 + ((c ^ (nl & 7)) << 3)];
            *(short8*)&dst[(size_t)nl * DHEAD + c * 8] = vv;
        }
    } else {
#pragma unroll
        for (int mt = 0; mt < 4; ++mt)
#pragma unroll
            for (int nt = 0; nt < 4; ++nt) {
                int nl = nt * 16 + l15;
                int swc = nl >> 3, swo = nl & 7;
#pragma unroll
                for (int r = 0; r < 4; ++r) {
                    int d = mt * 16 + quad * 4 + r;
                    myT[d * 64 + ((swc ^ (d & 7)) << 3) + swo] = (short)f2bf(acc[mt][nt][r]);
                }
            }
        unsigned short* dst = vb + (size_t)bh * DHEAD * NSEQ + n0 + wn * 64;
#pragma unroll
        for (int pass = 0; pass < 8; ++pass) {
            int d = pass * 8 + (lane >> 3), c = lane & 7;
            short8 vv = *(const short8*)&myT[d * 64 + ((c ^ (d & 7)) << 3)];
            *(short8*)&dst[(size_t)d * NSEQ + c * 8] = vv;
        }
    }
}

// ---------------------------------------------------------------------------
// k_attn v6: register-P (R11) + fine Kt swizzle (permuted A-row reads now
// 2-way/free) + packed bf16 cvt + hoisted V fragments.
// S^T = K·Q^T in two 16-row tiles with A-rows f_t(m)=(m>>2)*8+t*4+(m&3);
// tile t's C lands at PV B-operand elements t*4+r.  P never touches LDS.
// ---------------------------------------------------------------------------
__global__ __launch_bounds__(256, 2) void k_attn(
    const unsigned short* __restrict__ qh, const unsigned short* __restrict__ kh,
    const unsigned short* __restrict__ vb,
    unsigned short* __restrict__ aot, const float* __restrict__ Mptr) {
    __shared__ __align__(16) short Kt[2][64 * 64];
    __shared__ __align__(16) short Vt[2][64 * 64];
    const int tid = threadIdx.x, wave = tid >> 6, lane = tid & 63;
    const int l15 = lane & 15, quad = lane >> 4, q8 = quad * 8;
    const int flat = blockIdx.x;
    const int xcd = flat & 7, idx = flat >> 3;
    const int bh = xcd * 4 + (idx >> 4);
    const int i0 = (idx & 15) * 128;
    const int b = bh >> 4, h = bh & 15;
    const float Ms = *Mptr;
    const float4v mInit = (float4v){-Ms, -Ms, -Ms, -Ms};
    const int srow = tid >> 3;
    // Kt fine swizzle key (staging side): (row&3)|(((row>>3)&1)<<2); it-indep.
    const int kkey  = (srow & 3) | (((srow >> 3) & 1) << 2);
    const int cswzK = ((tid & 7) ^ kkey) * 8;
    const int cswzV = ((tid & 7) ^ (srow & 7)) * 8;
    // reader side: key(ar) folds to l15&7 (lane-constant)
    const int ksw = l15 & 7;
    const int kc0 = ((0 + quad) ^ ksw) * 8;
    const int kc1 = ((4 + quad) ^ ksw) * 8;
    // permuted A-row indices (within a 32-j chunk) for the two S^T tiles
    const int ar0 = (l15 >> 2) * 8 + (l15 & 3);
    const int ar1 = ar0 + 4;

    // Q fragments (B-operand of S^T): rows it*16+l15, d-slices quad*8
    short8 qf[2][2];
    {
        const short* qb = (const short*)qh + ((size_t)bh * NSEQ + i0 + wave * 32) * DHEAD;
#pragma unroll
        for (int it = 0; it < 2; ++it) {
            qf[it][0] = *(const short8*)&qb[(it * 16 + l15) * DHEAD + q8];
            qf[it][1] = *(const short8*)&qb[(it * 16 + l15) * DHEAD + 32 + q8];
        }
    }

    float4v of[2][4];
#pragma unroll
    for (int it = 0; it < 2; ++it)
#pragma unroll
        for (int dt = 0; dt < 4; ++dt) of[it][dt] = (float4v){0.f, 0.f, 0.f, 0.f};
    float l_acc[2] = {0.f, 0.f};

    const short* kbase = (const short*)kh + (size_t)bh * NSEQ * DHEAD;
    const short* vbase = (const short*)vb + (size_t)bh * DHEAD * NSEQ;

#pragma unroll
    for (int it = 0; it < 2; ++it) {
        int row = it * 32 + srow;
        cp16(kbase + (size_t)row * DHEAD + cswzK, &Kt[0][it * 2048 + wave * 512]);
        cp16(vbase + (size_t)row * NSEQ + cswzV, &Vt[0][it * 2048 + wave * 512]);
    }
    __syncthreads();

    int buf = 0;
    for (int j0 = 0; j0 < NSEQ; j0 += 64) {
        if (j0 + 64 < NSEQ) {
            int nb = buf ^ 1;
#pragma unroll
            for (int it = 0; it < 2; ++it) {
                int row = it * 32 + srow;
                cp16(kbase + (size_t)(j0 + 64 + row) * DHEAD + cswzK, &Kt[nb][it * 2048 + wave * 512]);
                cp16(vbase + (size_t)row * NSEQ + j0 + 64 + cswzV, &Vt[nb][it * 2048 + wave * 512]);
            }
        }

#pragma unroll
        for (int ch = 0; ch < 2; ++ch) {
            // hoist V fragments (independent of S chain -> overlaps MFMA)
            short8 av[4];
#pragma unroll
            for (int dt = 0; dt < 4; ++dt) {
                int vrow = dt * 16 + l15;
                av[dt] = *(const short8*)&Vt[buf][vrow * 64 + (((ch * 4 + quad) ^ (l15 & 7))) * 8];
            }
            int4v pw[2];
#pragma unroll
            for (int t = 0; t < 2; ++t) {
                const int arow = ch * 32 + (t ? ar1 : ar0);
                const short* kr = &Kt[buf][arow * 64];
                short8 kf0 = *(const short8*)&kr[kc0];
                short8 kf1 = *(const short8*)&kr[kc1];
#pragma unroll
                for (int it = 0; it < 2; ++it) {
                    float4v s = mInit;
                    s = __builtin_amdgcn_mfma_f32_16x16x32_bf16(kf0, qf[it][0], s, 0, 0, 0);
                    s = __builtin_amdgcn_mfma_f32_16x16x32_bf16(kf1, qf[it][1], s, 0, 0, 0);
                    float p0 = fexp2(s[0]);
                    float p1 = fexp2(s[1]);
                    float p2 = fexp2(s[2]);
                    float p3 = fexp2(s[3]);
                    l_acc[it] += (p0 + p1) + (p2 + p3);
                    pw[it][t * 2 + 0] = pack_bf16(p0, p1);
                    pw[it][t * 2 + 1] = pack_bf16(p2, p3);
                }
            }
            short8 pb0 = __builtin_bit_cast(short8, pw[0]);
            short8 pb1 = __builtin_bit_cast(short8, pw[1]);
#pragma unroll
            for (int dt = 0; dt < 4; ++dt) {
                of[0][dt] = __builtin_amdgcn_mfma_f32_16x16x32_bf16(av[dt], pb0, of[0][dt], 0, 0, 0);
                of[1][dt] = __builtin_amdgcn_mfma_f32_16x16x32_bf16(av[dt], pb1, of[1][dt], 0, 0, 0);
            }
        }

        __syncthreads();   // next buf staged + this buf consumed
        buf ^= 1;
    }

    // l per i: sum across the 4 quads; write normalized O^T rows
#pragma unroll
    for (int it = 0; it < 2; ++it) {
        float l = l_acc[it];
        l += __shfl_xor(l, 16);
        l += __shfl_xor(l, 32);
        float inv = 1.0f / fmaxf(l, 1e-30f);
        unsigned short* ob = aot + ((size_t)b * NSEQ + i0 + wave * 32 + it * 16 + l15) * HDIM + h * DHEAD;
#pragma unroll
        for (int dt = 0; dt < 4; ++dt) {
            ushort4 o;
            o.x = f2bf(of[it][dt][0] * inv);
            o.y = f2bf(of[it][dt][1] * inv);
            o.z = f2bf(of[it][dt][2] * inv);
            o.w = f2bf(of[it][dt][3] * inv);
            *(ushort4*)&ob[dt * 16 + quad * 4] = o;
        }
    }
}

// ---------------------------------------------------------------------------
// k_gemm_out: 64x64 tiles (512 blocks, 2/CU — R9 measured config).
// y[b][o][n] f32 = sum_c Wout[o][c]*aot[b][n][c] + bout[o]
// ---------------------------------------------------------------------------
__global__ __launch_bounds__(256) void k_gemm_out(
    const unsigned short* __restrict__ W, const unsigned short* __restrict__ aot,
    const float* __restrict__ bias, float* __restrict__ out) {
    constexpr int K = HDIM, N = NSEQ, M = CCH;
    __shared__ __align__(16) short lsA[64 * 64];
    __shared__ __align__(16) short lsB[64 * 64];
    const int tid = threadIdx.x, wave = tid >> 6, lane = tid & 63;
    const int l15 = lane & 15, quad = lane >> 4;
    const int n0 = blockIdx.x * 64, m0 = blockIdx.y * 64, z = blockIdx.z;
    const short* Ab = (const short*)W + (size_t)m0 * K;
    const short* Bb = (const short*)aot + ((size_t)z * N + n0) * K;
    const int wm = wave >> 1, wn = wave & 1;
    const int cswz = (((tid & 7) ^ ((tid >> 3) & 7))) * 8;
    const int sw7 = (l15 & 7);

    float4v acc[2][2];
#pragma unroll
    for (int i = 0; i < 2; ++i)
#pragma unroll
        for (int j = 0; j < 2; ++j) acc[i][j] = (float4v){0.f, 0.f, 0.f, 0.f};

    for (int k0 = 0; k0 < K; k0 += 64) {
        {
            int row = tid >> 3;
            cp16(Ab + (size_t)row * K + k0 + cswz, &lsA[wave * 512]);
            cp16(Ab + (size_t)(row + 32) * K + k0 + cswz, &lsA[2048 + wave * 512]);
            cp16(Bb + (size_t)row * K + k0 + cswz, &lsB[wave * 512]);
            cp16(Bb + (size_t)(row + 32) * K + k0 + cswz, &lsB[2048 + wave * 512]);
        }
        __syncthreads();
        short8 af[2][2], bfr[2][2];
#pragma unroll
        for (int t = 0; t < 2; ++t)
#pragma unroll
            for (int kk = 0; kk < 2; ++kk) {
                af[t][kk]  = *(const short8*)&lsA[(wm * 32 + t * 16 + l15) * 64 + ((kk * 4 + quad) ^ sw7) * 8];
                bfr[t][kk] = *(const short8*)&lsB[(wn * 32 + t * 16 + l15) * 64 + ((kk * 4 + quad) ^ sw7) * 8];
            }
#pragma unroll
        for (int mt = 0; mt < 2; ++mt)
#pragma unroll
            for (int nt = 0; nt < 2; ++nt) {
                acc[mt][nt] = __builtin_amdgcn_mfma_f32_16x16x32_bf16(af[mt][0], bfr[nt][0], acc[mt][nt], 0, 0, 0);
                acc[mt][nt] = __builtin_amdgcn_mfma_f32_16x16x32_bf16(af[mt][1], bfr[nt][1], acc[mt][nt], 0, 0, 0);
            }
        __syncthreads();
    }
    float* Co = out + (size_t)z * M * N;
#pragma unroll
    for (int mt = 0; mt < 2; ++mt)
#pragma unroll
        for (int nt = 0; nt < 2; ++nt) {
            int mrow = m0 + wm * 32 + mt * 16 + quad * 4;
#pragma unroll
            for (int r = 0; r < 4; ++r) {
                int mr = mrow + r;
                int nc = n0 + wn * 32 + nt * 16 + l15;
                Co[(size_t)mr * N + nc] = acc[mt][nt][r] + bias[mr];
            }
        }
}

// ---------------------------------------------------------------------------
// Launch.  Inputs resolved by element count (f32).
// ---------------------------------------------------------------------------
extern "C" void kernel_launch(void* const* d_in, const int* in_sizes, int n_in,
                              void* d_out, int out_size, void* d_ws, size_t ws_size,
                              hipStream_t stream) {
    const float* x = nullptr; const float* Wqkv = nullptr;
    const float* qs = nullptr; const float* ks = nullptr;
    const float* Wout = nullptr; const float* bout = nullptr;
    for (int i = 0; i < n_in; ++i) {
        switch (in_sizes[i]) {
            case BATCH * CCH * NSEQ: x    = (const float*)d_in[i]; break;
            case ODIM * CCH:         Wqkv = (const float*)d_in[i]; break;
            case CCH * HDIM:         Wout = (const float*)d_in[i]; break;
            case CCH:                bout = (const float*)d_in[i]; break;
            case DHEAD: if (!qs) qs = (const float*)d_in[i]; else ks = (const float*)d_in[i]; break;
            default: break;
        }
    }
    float* y = (float*)d_out;

    char* ws = (char*)d_ws;
    float*          Mbuf  = (float*)(ws + 0);
    unsigned short* Wqkvb = (unsigned short*)(ws + 4096);        // 3,145,728 B
    unsigned short* Woutb = (unsigned short*)(ws + 3149824);     // 1,048,576 B
    unsigned short* xt    = (unsigned short*)(ws + 4198400);     // 4,194,304 B
    unsigned short* qh    = (unsigned short*)(ws + 8392704);     // 8,388,608 B
    unsigned short* kh    = (unsigned short*)(ws + 16781312);    // 8,388,608 B
    unsigned short* vb    = (unsigned short*)(ws + 25169920);    // 8,388,608 B
    unsigned short* aot   = (unsigned short*)(ws + 33558528);    // 8,388,608 B -> 41,947,136

    k_prep<<<dim3(2048 + 512), 256, 0, stream>>>(Wqkv, Wout, x, qs, ks, Wqkvb, Woutb, xt, Mbuf);
    k_gemm_qkv<<<dim3(NSEQ / 128, ODIM / 128, BATCH), 256, 0, stream>>>(Wqkvb, xt, qs, ks, qh, kh, vb);
    k_attn<<<dim3(512), 256, 0, stream>>>(qh, kh, vb, aot, Mbuf);
    k_gemm_out<<<dim3(NSEQ / 64, CCH / 64, BATCH), 256, 0, stream>>>(Woutb, aot, bout, y);
}